// Round 7
// baseline (3324.160 us; speedup 1.0000x reference)
//
#include <hip/hip_runtime.h>
#include <hip/hip_bf16.h>
#include <stdint.h>

typedef __bf16 bf16x8 __attribute__((ext_vector_type(8)));
typedef float  f32x16 __attribute__((ext_vector_type(16)));

#define FMPX 19
#define NPOS 361
#define CCH  512
#define NB   16
#define NCLS 20
#define CONF_T 0.001f
#define NMS_TH 0.6f
#define BSCALE (32.0f/608.0f)

#define SC_OFF   (NB*NPOS*4)
#define CLS_OFF  (SC_OFF + NB*NPOS)
#define KEEP_OFF (CLS_OFF + NB*NPOS)

#define GSTR  3528                     // 441 rows * 8 ci elems
#define PLANE ((size_t)3612672)        // 16 b * 64 g * 3528
#define XBUF  24576                    // 3pl * 2kh * 4096B (252 rows*16B padded to 4096)
#define SMEMB 55296                    // max(2*XBUF=49152, Lf 4*96*36*4=55296)

__device__ __forceinline__ void gl_lds16(const void* g, void* l) {
  __builtin_amdgcn_global_load_lds(
      (const __attribute__((address_space(1))) unsigned int*)g,
      (__attribute__((address_space(3))) unsigned int*)l, 16, 0, 0);
}
#define MFMA32(A,B,C) __builtin_amdgcn_mfma_f32_32x32x16_bf16(A,B,C,0,0,0)
#define SBAR() __builtin_amdgcn_sched_barrier(0)
#define PRIO1 __builtin_amdgcn_s_setprio(1)
#define PRIO0 __builtin_amdgcn_s_setprio(0)

// tap byte offsets in padded-row LDS (goffs*16)
#define GOF0 (-352)
#define GOF1 (-336)
#define GOF2 (-320)
#define GOF3 (-16)
#define GOF4 (0)
#define GOF5 (16)
#define GOF6 (320)
#define GOF7 (336)
#define GOF8 (352)
#define GO16(T) (GOF##T)

// ---------------- split x: f32 NCHW -> 3 bf16 planes [pl][b][g][row441][8ci]
__global__ void split_x_k(const float* __restrict__ x, __bf16* __restrict__ Xd) {
  __shared__ float sx[8][368];
  int g = blockIdx.x, b = blockIdx.y;
  int tid = threadIdx.x;
  for (int i = tid; i < 8*361; i += 256) {
    int ci = i / 361, p = i - ci*361;
    sx[ci][p] = x[((size_t)b*CCH + g*8 + ci)*NPOS + p];
  }
  __syncthreads();
  for (int row = tid; row < 441; row += 256) {
    int y = row/21, xx = row - y*21;
    bf16x8 oh = {}, om = {}, ol = {};
    if (y >= 1 && y <= 19 && xx >= 1 && xx <= 19) {
      int p = (y-1)*19 + xx - 1;
#pragma unroll
      for (int j = 0; j < 8; ++j) {
        float v = sx[j][p];
        __bf16 hh = (__bf16)v; float r1 = v - (float)hh;
        __bf16 mm = (__bf16)r1;
        oh[j] = hh; om[j] = mm; ol[j] = (__bf16)(r1 - (float)mm);
      }
    }
    size_t o = (((size_t)b)*64 + g)*GSTR + (size_t)row*8;
    *(bf16x8*)(Xd + o)           = oh;
    *(bf16x8*)(Xd + PLANE + o)   = om;
    *(bf16x8*)(Xd + 2*PLANE + o) = ol;
  }
}

// ---------------- weight repack+split: w[co][ci][3][3] f32 ->
//  Wg [slice16][pl3][tap9][chunk32][kh2][co32][8ci] bf16
__global__ void repack_k(const float* __restrict__ w, __bf16* __restrict__ Wg) {
  __shared__ float sw[32][145];
  int slice = blockIdx.x, chunk = blockIdx.y;
  int tid = threadIdx.x;
  for (int i = tid; i < 32*144; i += 256) {
    int cl = i / 144, r = i - cl*144;
    sw[cl][r] = w[((size_t)slice*32 + cl)*4608 + chunk*144 + r];
  }
  __syncthreads();
  for (int u = tid; u < 1728; u += 256) {
    int co = u & 31, kh = (u >> 5) & 1, pt = u >> 6;
    int tap = pt % 9, pl = pt / 9;
    bf16x8 o;
#pragma unroll
    for (int j = 0; j < 8; ++j) {
      float v = sw[co][(kh*8 + j)*9 + tap];
      __bf16 hh = (__bf16)v; float r1 = v - (float)hh;
      __bf16 mm = (__bf16)r1;
      o[j] = pl == 0 ? hh : (pl == 1 ? mm : (__bf16)(r1 - (float)mm));
    }
    *(bf16x8*)(Wg + ((((size_t)slice*3 + pl)*9 + tap)*32 + chunk)*512 + kh*256 + co*8) = o;
  }
}

// B fragment from global (perfectly coalesced 1KB/wave, L2-resident via XCD pinning)
#define LW(PL, T, C) (*(const bf16x8*)(gWb + (size_t)(PL)*147456 + (T)*16384 + (C)*512))

#define RDA6(SP, PL, T) do { \
  SP##0 = *(const bf16x8*)(Xc + (PL)*8192 + kh4096 + aoff0 + GO16(T)); \
  SP##1 = *(const bf16x8*)(Xc + (PL)*8192 + kh4096 + aoff1 + GO16(T)); \
  SP##2 = *(const bf16x8*)(Xc + (PL)*8192 + kh4096 + aoff2 + GO16(T)); \
  SP##3 = *(const bf16x8*)(Xc + (PL)*8192 + kh4096 + aoff3 + GO16(T)); \
  SP##4 = *(const bf16x8*)(Xc + (PL)*8192 + kh4096 + aoff4 + GO16(T)); \
  SP##5 = *(const bf16x8*)(Xc + (PL)*8192 + kh4096 + aoff5 + GO16(T)); } while (0)

#define CL0(SP, BHX, BMX, BLX) do { PRIO1; \
  acc0 = MFMA32(SP##0, BHX, acc0); acc1 = MFMA32(SP##1, BHX, acc1); \
  acc2 = MFMA32(SP##2, BHX, acc2); acc3 = MFMA32(SP##3, BHX, acc3); \
  acc4 = MFMA32(SP##4, BHX, acc4); acc5 = MFMA32(SP##5, BHX, acc5); \
  acc0 = MFMA32(SP##0, BMX, acc0); acc1 = MFMA32(SP##1, BMX, acc1); \
  acc2 = MFMA32(SP##2, BMX, acc2); acc3 = MFMA32(SP##3, BMX, acc3); \
  acc4 = MFMA32(SP##4, BMX, acc4); acc5 = MFMA32(SP##5, BMX, acc5); \
  acc0 = MFMA32(SP##0, BLX, acc0); acc1 = MFMA32(SP##1, BLX, acc1); \
  acc2 = MFMA32(SP##2, BLX, acc2); acc3 = MFMA32(SP##3, BLX, acc3); \
  acc4 = MFMA32(SP##4, BLX, acc4); acc5 = MFMA32(SP##5, BLX, acc5); \
  PRIO0; } while (0)

#define CL1A(SP, BHX, BMX) do { PRIO1; \
  acc0 = MFMA32(SP##0, BHX, acc0); acc1 = MFMA32(SP##1, BHX, acc1); \
  acc2 = MFMA32(SP##2, BHX, acc2); acc3 = MFMA32(SP##3, BHX, acc3); \
  acc4 = MFMA32(SP##4, BHX, acc4); acc5 = MFMA32(SP##5, BHX, acc5); \
  acc0 = MFMA32(SP##0, BMX, acc0); acc1 = MFMA32(SP##1, BMX, acc1); \
  acc2 = MFMA32(SP##2, BMX, acc2); acc3 = MFMA32(SP##3, BMX, acc3); \
  acc4 = MFMA32(SP##4, BMX, acc4); acc5 = MFMA32(SP##5, BMX, acc5); \
  PRIO0; } while (0)

#define CL1B(SP, BHX) do { PRIO1; \
  acc0 = MFMA32(SP##0, BHX, acc0); acc1 = MFMA32(SP##1, BHX, acc1); \
  acc2 = MFMA32(SP##2, BHX, acc2); acc3 = MFMA32(SP##3, BHX, acc3); \
  acc4 = MFMA32(SP##4, BHX, acc4); acc5 = MFMA32(SP##5, BHX, acc5); \
  PRIO0; } while (0)

#define STO(A, MTL) do { _Pragma("unroll") \
  for (int r = 0; r < 16; ++r) { \
    Lf[wq*3456 + ((MTL)*32 + 4*kh + (r & 3) + 8*(r >> 2))*36 + col] = (A)[r]; } } while (0)

// ---------------- 3x3 conv: grid 512, 256 thr = 4 waves (s,tg)
// bid decode pins each co-slice pair to one XCD (XCD = bid%8) so the slice's
// W (884KB x 2 = 1.77MB) stays L2-resident; B streams global->reg as L2 hits.
// wave: 6 m-tiles x 32 co; A from LDS (double-buffered).
__global__ __launch_bounds__(256, 2) void conv3x3_mfma(
    const __bf16* __restrict__ Xs, const __bf16* __restrict__ Wg,
    const float* __restrict__ bias, __bf16* __restrict__ Xd)
{
  __shared__ __attribute__((aligned(16))) char smem[SMEMB];
  const int tid = threadIdx.x;
  const int bid = blockIdx.x;
  const int slice = (bid & 7)*2 + ((bid >> 3) & 1);   // XCD-pinned slice
  const int b = (bid >> 4) & 15, h = bid >> 8;
  const int lane = tid & 63;
  const int wq = __builtin_amdgcn_readfirstlane(tid >> 6);
  const int s = wq & 1, tg = wq >> 1;
  const int col = lane & 31, kh = lane >> 5;
  const int kh4096 = kh*4096;
  const int PB = h*190, CNT = h ? 171 : 190;
  const int PEND = PB + CNT - 1;

  // A LDS byte offsets per m-tile (local padded row * 16)
  int aoff0, aoff1, aoff2, aoff3, aoff4, aoff5;
  {
    int ao[6];
#pragma unroll
    for (int mt = 0; mt < 6; ++mt) {
      int p = PB + mt*32 + col; if (p > PEND) p = PEND;
      int pp = p + 2*(p/19) + 22;
      ao[mt] = (pp - h*210)*16;
    }
    aoff0 = ao[0]; aoff1 = ao[1]; aoff2 = ao[2];
    aoff3 = ao[3]; aoff4 = ao[4]; aoff5 = ao[5];
  }
  const __bf16* gWb = Wg + (size_t)slice*442368 + (size_t)lane*8;
  const int clampU = h ? 230 : 251;

  auto stageX = [&](int c1, int buf) {
#pragma unroll
    for (int r = 0; r < 6; ++r) {
      const int i = wq*6 + r;
      const int pl = i >> 3, khs = (i >> 2) & 1, j = i & 3;
      int u = j*64 + lane; if (u > clampU) u = clampU;
      gl_lds16(Xs + ((size_t)pl*16 + b)*64*GSTR + (size_t)(2*c1 + khs)*GSTR
                   + (size_t)(h*210 + u)*8,
               smem + buf*XBUF + (pl*2 + khs)*4096 + j*1024);
    }
  };

  f32x16 acc0 = {}, acc1 = {}, acc2 = {}, acc3 = {}, acc4 = {}, acc5 = {};

  stageX(0, 0);
  __syncthreads();

  for (int c = 0; c < 32; ++c) {
    const char* Xc = smem + (c & 1)*XBUF;
    if (s == 0) {
      bf16x8 Aa0, Aa1, Aa2, Aa3, Aa4, Aa5, Ab0, Ab1, Ab2, Ab3, Ab4, Ab5;
      bf16x8 BH[5], BM[5], BL[5];
      if (tg == 0) {   // taps 0..3, products Ah*(Bh,Bm,Bl)
        RDA6(Aa, 0, 0);
#pragma unroll
        for (int k2 = 0; k2 < 4; ++k2) {
          BH[k2] = LW(0, k2, c); BM[k2] = LW(1, k2, c); BL[k2] = LW(2, k2, c);
        }
        if (c < 31) stageX(c + 1, (c + 1) & 1);
        SBAR();
        RDA6(Ab, 0, 1); SBAR(); CL0(Aa, BH[0], BM[0], BL[0]); SBAR();
        RDA6(Aa, 0, 2); SBAR(); CL0(Ab, BH[1], BM[1], BL[1]); SBAR();
        RDA6(Ab, 0, 3); SBAR(); CL0(Aa, BH[2], BM[2], BL[2]); SBAR();
        CL0(Ab, BH[3], BM[3], BL[3]);
      } else {         // taps 4..8
        RDA6(Aa, 0, 4);
#pragma unroll
        for (int k2 = 0; k2 < 5; ++k2) {
          BH[k2] = LW(0, 4 + k2, c); BM[k2] = LW(1, 4 + k2, c); BL[k2] = LW(2, 4 + k2, c);
        }
        if (c < 31) stageX(c + 1, (c + 1) & 1);
        SBAR();
        RDA6(Ab, 0, 5); SBAR(); CL0(Aa, BH[0], BM[0], BL[0]); SBAR();
        RDA6(Aa, 0, 6); SBAR(); CL0(Ab, BH[1], BM[1], BL[1]); SBAR();
        RDA6(Ab, 0, 7); SBAR(); CL0(Aa, BH[2], BM[2], BL[2]); SBAR();
        RDA6(Aa, 0, 8); SBAR(); CL0(Ab, BH[3], BM[3], BL[3]); SBAR();
        CL0(Aa, BH[4], BM[4], BL[4]);
      }
    } else {
      bf16x8 Ma0, Ma1, Ma2, Ma3, Ma4, Ma5, Mb0, Mb1, Mb2, Mb3, Mb4, Mb5;
      bf16x8 L0, L1, L2, L3, L4, L5;
      bf16x8 BH[5], BM[5];
      if (tg == 0) {   // taps 0..3, products Am*(Bh,Bm) + Al*Bh
        RDA6(Ma, 1, 0);
#pragma unroll
        for (int k2 = 0; k2 < 4; ++k2) { BH[k2] = LW(0, k2, c); BM[k2] = LW(1, k2, c); }
        if (c < 31) stageX(c + 1, (c + 1) & 1);
        SBAR();
        RDA6(L, 2, 0); RDA6(Mb, 1, 1); SBAR();
        CL1A(Ma, BH[0], BM[0]); CL1B(L, BH[0]); SBAR();
        RDA6(L, 2, 1); RDA6(Ma, 1, 2); SBAR();
        CL1A(Mb, BH[1], BM[1]); CL1B(L, BH[1]); SBAR();
        RDA6(L, 2, 2); RDA6(Mb, 1, 3); SBAR();
        CL1A(Ma, BH[2], BM[2]); CL1B(L, BH[2]); SBAR();
        RDA6(L, 2, 3); SBAR();
        CL1A(Mb, BH[3], BM[3]); CL1B(L, BH[3]);
      } else {         // taps 4..8
        RDA6(Ma, 1, 4);
#pragma unroll
        for (int k2 = 0; k2 < 5; ++k2) { BH[k2] = LW(0, 4 + k2, c); BM[k2] = LW(1, 4 + k2, c); }
        if (c < 31) stageX(c + 1, (c + 1) & 1);
        SBAR();
        RDA6(L, 2, 4); RDA6(Mb, 1, 5); SBAR();
        CL1A(Ma, BH[0], BM[0]); CL1B(L, BH[0]); SBAR();
        RDA6(L, 2, 5); RDA6(Ma, 1, 6); SBAR();
        CL1A(Mb, BH[1], BM[1]); CL1B(L, BH[1]); SBAR();
        RDA6(L, 2, 6); RDA6(Mb, 1, 7); SBAR();
        CL1A(Ma, BH[2], BM[2]); CL1B(L, BH[2]); SBAR();
        RDA6(L, 2, 7); RDA6(Ma, 1, 8); SBAR();
        CL1A(Mb, BH[3], BM[3]); CL1B(L, BH[3]); SBAR();
        RDA6(L, 2, 8); SBAR();
        CL1A(Ma, BH[4], BM[4]); CL1B(L, BH[4]);
      }
    }
    __syncthreads();
  }

  // epilogue: two mt-halves; 4 partials in Lf[4][96][36]; combine+bias+leaky+split
  float* Lf = (float*)smem;
#pragma unroll
  for (int half = 0; half < 2; ++half) {
    if (half == 0) { STO(acc0, 0); STO(acc1, 1); STO(acc2, 2); }
    else           { STO(acc3, 0); STO(acc4, 1); STO(acc5, 2); }
    __syncthreads();
    for (int u = tid; u < 1152; u += 256) {
      int pl = u / 384, rem = u - pl*384;
      int gq = rem / 96, lp = rem - gq*96;
      int lpos = half*96 + lp;
      if (lpos < CNT) {
        int p = PB + lpos;
        int pp = p + 2*(p/19) + 22;
        const float* bb = bias + slice*32 + gq*8;
        bf16x8 o;
#pragma unroll
        for (int j = 0; j < 8; ++j) {
          int coix = lp*36 + gq*8 + j;
          float v = Lf[coix] + Lf[3456 + coix] + Lf[6912 + coix] + Lf[10368 + coix] + bb[j];
          v = v > 0.f ? v : 0.1f*v;
          __bf16 hh = (__bf16)v; float r1 = v - (float)hh;
          __bf16 mm = (__bf16)r1;
          o[j] = pl == 0 ? hh : (pl == 1 ? mm : (__bf16)(r1 - (float)mm));
        }
        *(bf16x8*)(Xd + (((size_t)pl*16 + b)*64 + slice*4 + gq)*GSTR + (size_t)pp*8) = o;
      }
    }
    __syncthreads();
  }

  // zero output halo rows for this h-half (consumers need zero padding)
  // halo columns are x=0 and x=20 of each padded row (x=19 is VALID output!)
  const int nh = h ? 39 : 41;
  for (int u = tid; u < 12*nh; u += 256) {
    int pl = u / (4*nh); int rem = u - pl*4*nh;
    int gq = rem / nh; int ci2 = rem - gq*nh;
    int rowpos;
    if (ci2 < 21) rowpos = h ? (420 + ci2) : ci2;
    else { int q = ci2 - 21; rowpos = ((h ? 11 : 1) + (q >> 1))*21 + 20*(q & 1); }
    bf16x8 z = {};
    *(bf16x8*)(Xd + (((size_t)pl*16 + b)*64 + slice*4 + gq)*GSTR + (size_t)rowpos*8) = z;
  }
}

// ---------------- 1x1 heads on split planes ----------------
__global__ __launch_bounds__(256) void head_rf_k(
    const __bf16* __restrict__ F, const float* __restrict__ wobj,
    const float* __restrict__ bobj, const float* __restrict__ wreg,
    const float* __restrict__ breg, float* __restrict__ obj, float* __restrict__ regp)
{
  int gw = blockIdx.x*4 + (threadIdx.x >> 6);
  if (gw >= NB*NPOS) return;
  int lane = threadIdx.x & 63;
  int b = gw / NPOS, p = gw % NPOS;
  int pp = p + 2*(p/19) + 22;
  const __bf16* base = F + (((size_t)b)*64 + lane)*GSTR + (size_t)pp*8;
  bf16x8 v0 = *(const bf16x8*)base;
  bf16x8 v1 = *(const bf16x8*)(base + PLANE);
  bf16x8 v2 = *(const bf16x8*)(base + 2*PLANE);
  float f[8];
#pragma unroll
  for (int j = 0; j < 8; ++j) f[j] = (float)v0[j] + (float)v1[j] + (float)v2[j];
#pragma unroll
  for (int o = 0; o < 5; ++o) {
    const float* wp = (o == 0) ? wobj : wreg + (o-1)*CCH;
    float4 wa = *(const float4*)(wp + lane*8);
    float4 wb = *(const float4*)(wp + lane*8 + 4);
    float s2 = f[0]*wa.x + f[1]*wa.y + f[2]*wa.z + f[3]*wa.w
             + f[4]*wb.x + f[5]*wb.y + f[6]*wb.z + f[7]*wb.w;
#pragma unroll
    for (int d = 32; d; d >>= 1) s2 += __shfl_xor(s2, d);
    if (lane == 0) {
      if (o == 0) obj[gw] = s2 + bobj[0];
      else regp[(size_t)gw*4 + (o-1)] = s2 + breg[o-1];
    }
  }
}

__global__ __launch_bounds__(256) void head_cls_k(
    const __bf16* __restrict__ F, const float* __restrict__ wcls,
    const float* __restrict__ bcls, float* __restrict__ clsp)
{
  int gw = blockIdx.x*4 + (threadIdx.x >> 6);
  if (gw >= NB*NPOS) return;
  int lane = threadIdx.x & 63;
  int b = gw / NPOS, p = gw % NPOS;
  int pp = p + 2*(p/19) + 22;
  const __bf16* base = F + (((size_t)b)*64 + lane)*GSTR + (size_t)pp*8;
  bf16x8 v0 = *(const bf16x8*)base;
  bf16x8 v1 = *(const bf16x8*)(base + PLANE);
  bf16x8 v2 = *(const bf16x8*)(base + 2*PLANE);
  float f[8];
#pragma unroll
  for (int j = 0; j < 8; ++j) f[j] = (float)v0[j] + (float)v1[j] + (float)v2[j];
#pragma unroll
  for (int o = 0; o < NCLS; ++o) {
    const float* wp = wcls + o*CCH;
    float4 wa = *(const float4*)(wp + lane*8);
    float4 wb = *(const float4*)(wp + lane*8 + 4);
    float s2 = f[0]*wa.x + f[1]*wa.y + f[2]*wa.z + f[3]*wa.w
             + f[4]*wb.x + f[5]*wb.y + f[6]*wb.z + f[7]*wb.w;
#pragma unroll
    for (int d = 32; d; d >>= 1) s2 += __shfl_xor(s2, d);
    if (lane == 0) clsp[(size_t)gw*NCLS + o] = s2 + bcls[o];
  }
}

// ---------------- decode boxes + scores + argmax -------------------------
__global__ void decode_k(const float* __restrict__ obj, const float* __restrict__ clsp,
                         const float* __restrict__ regp, float* __restrict__ outb)
{
  int i = blockIdx.x * 256 + threadIdx.x;
  if (i >= NB * NPOS) return;
  int p = i % NPOS;
  float gx = (float)(p % FMPX), gy = (float)(p / FMPX);
  float4 rg = *(const float4*)&regp[(size_t)i * 4];
  float cx = 1.f / (1.f + expf(-rg.x)) + gx;
  float cy = 1.f / (1.f + expf(-rg.y)) + gy;
  float whw = expf(rg.z), whh = expf(rg.w);
  float x1 = fminf(fmaxf((cx - whw * 0.5f) * BSCALE, 0.f), 1.f);
  float y1 = fminf(fmaxf((cy - whh * 0.5f) * BSCALE, 0.f), 1.f);
  float x2 = fminf(fmaxf((cx + whw * 0.5f) * BSCALE, 0.f), 1.f);
  float y2 = fminf(fmaxf((cy + whh * 0.5f) * BSCALE, 0.f), 1.f);
  outb[(size_t)i * 4 + 0] = x1; outb[(size_t)i * 4 + 1] = y1;
  outb[(size_t)i * 4 + 2] = x2; outb[(size_t)i * 4 + 3] = y2;

  float so = 1.f / (1.f + expf(-obj[i]));
  float cv[20];
  const float4* cp = (const float4*)&clsp[(size_t)i * 20];
#pragma unroll
  for (int q = 0; q < 5; q++) {
    float4 v4 = cp[q];
    cv[q * 4] = v4.x; cv[q * 4 + 1] = v4.y; cv[q * 4 + 2] = v4.z; cv[q * 4 + 3] = v4.w;
  }
  float mx = cv[0];
#pragma unroll
  for (int c = 1; c < 20; c++) mx = fmaxf(mx, cv[c]);
  float sum = 0.f;
#pragma unroll
  for (int c = 0; c < 20; c++) { cv[c] = expf(cv[c] - mx); sum += cv[c]; }
  float inv = so / sum;
  float best = -1.f; int bi = 0;
#pragma unroll
  for (int c = 0; c < 20; c++) { float s = cv[c] * inv; if (s > best) { best = s; bi = c; } }
  outb[SC_OFF + i] = best;
  outb[CLS_OFF + i] = (float)bi;
  outb[KEEP_OFF + i] = 0.f;
}

// ---------------- per (batch,class) greedy NMS ----------------------------
__device__ inline unsigned ordf(float f) {
  unsigned u = __float_as_uint(f);
  return (u & 0x80000000u) ? ~u : (u | 0x80000000u);
}

__global__ __launch_bounds__(64) void nms_k(const float* __restrict__ outb, float* __restrict__ keep_out)
{
  int b = blockIdx.x / NCLS, c = blockIdx.x % NCLS;
  int lane = threadIdx.x;
  __shared__ unsigned long long keys[512];
  __shared__ float bx1[384], by1[384], bx2[384], by2[384], bar[384];
  __shared__ unsigned kp[384];
  __shared__ int sj[384];

  for (int i = lane; i < 512; i += 64) {
    unsigned long long key = 0ULL;
    if (i < NPOS) {
      float sc = outb[SC_OFF + b * NPOS + i];
      int ci = (int)outb[CLS_OFF + b * NPOS + i];
      float s = (ci == c && sc >= CONF_T) ? sc : -1.0f;
      key = ((unsigned long long)ordf(s) << 32) | (unsigned)(~(unsigned)i);
    }
    keys[i] = key;
  }
  __syncthreads();
  for (int kk = 2; kk <= 512; kk <<= 1) {
    for (int jj = kk >> 1; jj > 0; jj >>= 1) {
      for (int i = lane; i < 512; i += 64) {
        int l2 = i ^ jj;
        if (l2 > i) {
          unsigned long long a = keys[i], bb2 = keys[l2];
          bool dir = (i & kk) == 0;
          bool sw = dir ? (a < bb2) : (a > bb2);
          if (sw) { keys[i] = bb2; keys[l2] = a; }
        }
      }
      __syncthreads();
    }
  }
  unsigned ordc = ordf(CONF_T);
  int nvalid = 0;
  for (int i = lane; i < 384; i += 64) {
    unsigned long long key = keys[i];
    unsigned hi = (unsigned)(key >> 32);
    int j = (int)(~(unsigned)key);
    bool valid = (key != 0ULL) && (hi >= ordc);
    kp[i] = valid ? 1u : 0u;
    if (valid) {
      const float* bp = &outb[(size_t)(b * NPOS + j) * 4];
      float x1 = bp[0], y1 = bp[1], x2 = bp[2], y2 = bp[3];
      bx1[i] = x1; by1[i] = y1; bx2[i] = x2; by2[i] = y2;
      bar[i] = (x2 - x1) * (y2 - y1);
      sj[i] = j;
    } else { bx1[i] = 0; by1[i] = 0; bx2[i] = 0; by2[i] = 0; bar[i] = 0; sj[i] = 0; }
    nvalid += __popcll(__ballot(valid));
  }
  __syncthreads();
  for (int i = 0; i < nvalid; ++i) {
    if (kp[i]) {
      float x1i = bx1[i], y1i = by1[i], x2i = bx2[i], y2i = by2[i], ai = bar[i];
      for (int j2 = i + 1 + lane; j2 < nvalid; j2 += 64) {
        if (kp[j2]) {
          float ww = fmaxf(1e-28f, fminf(x2i, bx2[j2]) - fmaxf(x1i, bx1[j2]));
          float hh = fmaxf(1e-28f, fminf(y2i, by2[j2]) - fmaxf(y1i, by1[j2]));
          float inter = ww * hh;
          float iou = inter / (ai + bar[j2] - inter + 1e-14f);
          if (iou > NMS_TH) kp[j2] = 0u;
        }
      }
    }
    __syncthreads();
  }
  for (int i = lane; i < 384; i += 64)
    if (kp[i]) keep_out[b * NPOS + sj[i]] = 1.0f;
}

extern "C" void kernel_launch(void* const* d_in, const int* in_sizes, int n_in,
                              void* d_out, int out_size, void* d_ws, size_t ws_size,
                              hipStream_t stream)
{
  const float* x      = (const float*)d_in[0];
  const float* w_cls1 = (const float*)d_in[1];  const float* b_cls1 = (const float*)d_in[2];
  const float* w_cls2 = (const float*)d_in[3];  const float* b_cls2 = (const float*)d_in[4];
  const float* w_reg1 = (const float*)d_in[5];  const float* b_reg1 = (const float*)d_in[6];
  const float* w_reg2 = (const float*)d_in[7];  const float* b_reg2 = (const float*)d_in[8];
  const float* w_reg3 = (const float*)d_in[9];  const float* b_reg3 = (const float*)d_in[10];
  const float* w_reg4 = (const float*)d_in[11]; const float* b_reg4 = (const float*)d_in[12];
  const float* w_obj  = (const float*)d_in[13]; const float* b_obj  = (const float*)d_in[14];
  const float* w_clsh = (const float*)d_in[15]; const float* b_clsh = (const float*)d_in[16];
  const float* w_regh = (const float*)d_in[17]; const float* b_regh = (const float*)d_in[18];
  float* outb = (float*)d_out;

  __bf16* XsA = (__bf16*)d_ws;
  __bf16* XsB = XsA + 3*PLANE;
  __bf16* Wg  = XsB + 3*PLANE;
  float* obj  = (float*)(Wg + (size_t)7077888);
  float* regp = obj + NB*NPOS;
  float* clsp = regp + (size_t)NB*NPOS*4;

  auto conv = [&](const float* wsrc, const float* bsrc, const __bf16* src, __bf16* dst) {
    repack_k<<<dim3(16, 32), 256, 0, stream>>>(wsrc, Wg);
    conv3x3_mfma<<<512, 256, 0, stream>>>(src, Wg, bsrc, dst);
  };

  split_x_k<<<dim3(64, NB), 256, 0, stream>>>(x, XsA);
  conv(w_reg1, b_reg1, XsA, XsB);
  conv(w_reg2, b_reg2, XsB, XsA);
  conv(w_reg3, b_reg3, XsA, XsB);
  conv(w_reg4, b_reg4, XsB, XsA);                    // rf = XsA
  head_rf_k<<<1444, 256, 0, stream>>>(XsA, w_obj, b_obj, w_regh, b_regh, obj, regp);
  split_x_k<<<dim3(64, NB), 256, 0, stream>>>(x, XsB);
  conv(w_cls1, b_cls1, XsB, XsA);
  conv(w_cls2, b_cls2, XsA, XsB);                    // cf = XsB
  head_cls_k<<<1444, 256, 0, stream>>>(XsB, w_clsh, b_clsh, clsp);
  decode_k<<<(NB * NPOS + 255) / 256, 256, 0, stream>>>(obj, clsp, regp, outb);
  nms_k<<<NB * NCLS, 64, 0, stream>>>(outb, outb + KEEP_OFF);
}

// Round 8
// 1689.370 us; speedup vs baseline: 1.9677x; 1.9677x over previous
//
#include <hip/hip_runtime.h>
#include <hip/hip_bf16.h>
#include <stdint.h>

typedef __bf16 bf16x8 __attribute__((ext_vector_type(8)));
typedef float  f32x16 __attribute__((ext_vector_type(16)));

#define FMPX 19
#define NPOS 361
#define CCH  512
#define NB   16
#define NCLS 20
#define CONF_T 0.001f
#define NMS_TH 0.6f
#define BSCALE (32.0f/608.0f)

#define SC_OFF   (NB*NPOS*4)
#define CLS_OFF  (SC_OFF + NB*NPOS)
#define KEEP_OFF (CLS_OFF + NB*NPOS)

#define GSTR  3528                     // 441 rows * 8 ci elems
#define PLANE ((size_t)3612672)        // 16 b * 64 g * 3528 elems per split plane
#define WSL   294912                   // W elems per slice: 2pl*9t*32ch*512
#define XBUF  16384                    // 2pl * 2kh * 4096B
#define WBUF  18432                    // 2pl * 9tap * 2kh * 32co * 16B
#define WOFF  32768                    // 2*XBUF
#define SMEMB 69632                    // 2*XBUF + 2*WBUF (>= Lf 55296)

__device__ __forceinline__ void gl_lds16(const void* g, void* l) {
  __builtin_amdgcn_global_load_lds(
      (const __attribute__((address_space(1))) unsigned int*)g,
      (__attribute__((address_space(3))) unsigned int*)l, 16, 0, 0);
}
#define MFMA32(A,B,C) __builtin_amdgcn_mfma_f32_32x32x16_bf16(A,B,C,0,0,0)
#define SBAR() __builtin_amdgcn_sched_barrier(0)
#define PRIO1 __builtin_amdgcn_s_setprio(1)
#define PRIO0 __builtin_amdgcn_s_setprio(0)

// tap byte offsets in padded-row LDS (goffs*16)
#define GOF0 (-352)
#define GOF1 (-336)
#define GOF2 (-320)
#define GOF3 (-16)
#define GOF4 (0)
#define GOF5 (16)
#define GOF6 (320)
#define GOF7 (336)
#define GOF8 (352)
#define GO16(T) (GOF##T)

// ---------------- split x: f32 NCHW -> 2 bf16 planes [pl][b][g][row441][8ci]
__global__ void split_x_k(const float* __restrict__ x, __bf16* __restrict__ Xd) {
  __shared__ float sx[8][368];
  int g = blockIdx.x, b = blockIdx.y;
  int tid = threadIdx.x;
  for (int i = tid; i < 8*361; i += 256) {
    int ci = i / 361, p = i - ci*361;
    sx[ci][p] = x[((size_t)b*CCH + g*8 + ci)*NPOS + p];
  }
  __syncthreads();
  for (int row = tid; row < 441; row += 256) {
    int y = row/21, xx = row - y*21;
    bf16x8 oh = {}, om = {};
    if (y >= 1 && y <= 19 && xx >= 1 && xx <= 19) {
      int p = (y-1)*19 + xx - 1;
#pragma unroll
      for (int j = 0; j < 8; ++j) {
        float v = sx[j][p];
        __bf16 hh = (__bf16)v;
        oh[j] = hh; om[j] = (__bf16)(v - (float)hh);
      }
    }
    size_t o = (((size_t)b)*64 + g)*GSTR + (size_t)row*8;
    *(bf16x8*)(Xd + o)         = oh;
    *(bf16x8*)(Xd + PLANE + o) = om;
  }
}

// ---------------- weight repack+split: w[co][ci][3][3] f32 ->
//  Wg [slice16][pl2][tap9][chunk32][kh2][co32][8ci] bf16
__global__ void repack_k(const float* __restrict__ w, __bf16* __restrict__ Wg) {
  __shared__ float sw[32][145];
  int slice = blockIdx.x, chunk = blockIdx.y;
  int tid = threadIdx.x;
  for (int i = tid; i < 32*144; i += 256) {
    int cl = i / 144, r = i - cl*144;
    sw[cl][r] = w[((size_t)slice*32 + cl)*4608 + chunk*144 + r];
  }
  __syncthreads();
  for (int u = tid; u < 1152; u += 256) {
    int co = u & 31, kh = (u >> 5) & 1, pt = u >> 6;   // pt 0..17
    int tap = pt % 9, pl = pt / 9;
    bf16x8 o;
#pragma unroll
    for (int j = 0; j < 8; ++j) {
      float v = sw[co][(kh*8 + j)*9 + tap];
      __bf16 hh = (__bf16)v;
      o[j] = pl == 0 ? hh : (__bf16)(v - (float)hh);
    }
    *(bf16x8*)(Wg + (((size_t)(slice*2 + pl)*9 + tap)*32 + chunk)*512 + kh*256 + co*8) = o;
  }
}

#define RDA6(SP, T) do { \
  SP##0 = *(const bf16x8*)(Xc + aoff0 + GO16(T)); \
  SP##1 = *(const bf16x8*)(Xc + aoff1 + GO16(T)); \
  SP##2 = *(const bf16x8*)(Xc + aoff2 + GO16(T)); \
  SP##3 = *(const bf16x8*)(Xc + aoff3 + GO16(T)); \
  SP##4 = *(const bf16x8*)(Xc + aoff4 + GO16(T)); \
  SP##5 = *(const bf16x8*)(Xc + aoff5 + GO16(T)); } while (0)

#define RDB(BH_, BM_, T) do { \
  BH_ = *(const bf16x8*)(Wc + (T)*1024 + boff); \
  BM_ = *(const bf16x8*)(Wc + 9216 + (T)*1024 + boff); } while (0)

#define CL(SP, BH_, BM_) do { PRIO1; \
  acc0 = MFMA32(SP##0, BH_, acc0); acc1 = MFMA32(SP##1, BH_, acc1); \
  acc2 = MFMA32(SP##2, BH_, acc2); acc3 = MFMA32(SP##3, BH_, acc3); \
  acc4 = MFMA32(SP##4, BH_, acc4); acc5 = MFMA32(SP##5, BH_, acc5); \
  acc0 = MFMA32(SP##0, BM_, acc0); acc1 = MFMA32(SP##1, BM_, acc1); \
  acc2 = MFMA32(SP##2, BM_, acc2); acc3 = MFMA32(SP##3, BM_, acc3); \
  acc4 = MFMA32(SP##4, BM_, acc4); acc5 = MFMA32(SP##5, BM_, acc5); \
  PRIO0; } while (0)

#define STO(A, MTL) do { _Pragma("unroll") \
  for (int r = 0; r < 16; ++r) { \
    Lf[wq*3456 + ((MTL)*32 + 4*kh + (r & 3) + 8*(r >> 2))*36 + col] = (A)[r]; } } while (0)

// ---------------- 3x3 conv: bf16x2, 4 products {hh,hm,mh,mm}
// grid 512 (b,slice,h); block 256 = 4 waves: pg (A-plane h/m) x tg (taps 0-4/5-8)
// wave: 6 m-tiles x 32 co; A and W both LDS-staged (double-buffered), 2 blocks/CU
__global__ __launch_bounds__(256, 2) void conv3x3_mfma(
    const __bf16* __restrict__ Xs, const __bf16* __restrict__ Wg,
    const float* __restrict__ bias, __bf16* __restrict__ Xd)
{
  __shared__ __attribute__((aligned(16))) char smem[SMEMB];
  const int tid = threadIdx.x;
  const int bid = blockIdx.x;
  const int b = bid & 15, slice = (bid >> 4) & 15, h = bid >> 8;
  const int lane = tid & 63;
  const int wq = __builtin_amdgcn_readfirstlane(tid >> 6);
  const int pg = wq & 1, tg = wq >> 1;
  const int col = lane & 31, kh = lane >> 5;
  const int PB = h*190, CNT = h ? 171 : 190;
  const int PEND = PB + CNT - 1;
  const int clampU = h ? 230 : 251;

  // A LDS byte offsets per m-tile (local padded row * 16), within (pg,kh) slot
  int aoff0, aoff1, aoff2, aoff3, aoff4, aoff5;
  {
    int ao[6];
#pragma unroll
    for (int mt = 0; mt < 6; ++mt) {
      int p = PB + mt*32 + col; if (p > PEND) p = PEND;
      int pp = p + 2*(p/19) + 22;
      ao[mt] = (pp - h*210)*16;
    }
    aoff0 = ao[0]; aoff1 = ao[1]; aoff2 = ao[2];
    aoff3 = ao[3]; aoff4 = ao[4]; aoff5 = ao[5];
  }
  const int boff = kh*512 + col*16;

  // staging descriptors: 34 insts total (16 X + 18 W), wave r-slots: i = wq + 4r
  const __bf16* sbase[9]; int sdst[9]; int sstep[9]; int sbad[9]; bool sval[9];
#pragma unroll
  for (int r = 0; r < 9; ++r) {
    int i = wq + 4*r;
    sval[r] = i < 34;
    int ic = sval[r] ? i : 0;
    if (ic < 16) {
      int pl = ic >> 3, khs = (ic >> 2) & 1, j = ic & 3;
      int u = j*64 + lane; if (u > clampU) u = clampU;
      sbase[r] = Xs + ((size_t)pl*16 + b)*64*GSTR + (size_t)khs*GSTR + (size_t)(h*210 + u)*8;
      sstep[r] = 2*GSTR;                       // elems per chunk
      sdst[r] = (pl*2 + khs)*4096 + j*1024;
      sbad[r] = XBUF;
    } else {
      int k = ic - 16;
      int pl = k/9, tap = k - pl*9;
      sbase[r] = Wg + (size_t)slice*WSL + (size_t)((pl*9 + tap)*32)*512 + (size_t)lane*8;
      sstep[r] = 512;
      sdst[r] = WOFF + pl*9216 + tap*1024;
      sbad[r] = WBUF;
    }
  }
  auto stage = [&](int c1, int buf) {
#pragma unroll
    for (int r = 0; r < 9; ++r)
      if (sval[r])
        gl_lds16(sbase[r] + (size_t)c1*sstep[r], smem + sdst[r] + (buf ? sbad[r] : 0));
  };

  f32x16 acc0 = {}, acc1 = {}, acc2 = {}, acc3 = {}, acc4 = {}, acc5 = {};

  stage(0, 0);
  __syncthreads();

  for (int c = 0; c < 32; ++c) {
    const char* Xc = smem + (c & 1)*XBUF + pg*8192 + kh*4096;
    const char* Wc = smem + WOFF + (c & 1)*WBUF;
    if (c < 31) stage(c + 1, (c + 1) & 1);

    bf16x8 Aa0, Aa1, Aa2, Aa3, Aa4, Aa5, Ab0, Ab1, Ab2, Ab3, Ab4, Ab5;
    bf16x8 Bh0, Bm0, Bh1, Bm1;
    if (tg == 0) {   // taps 0..4
      RDA6(Aa, 0); RDB(Bh0, Bm0, 0); SBAR();
      RDA6(Ab, 1); RDB(Bh1, Bm1, 1); SBAR(); CL(Aa, Bh0, Bm0); SBAR();
      RDA6(Aa, 2); RDB(Bh0, Bm0, 2); SBAR(); CL(Ab, Bh1, Bm1); SBAR();
      RDA6(Ab, 3); RDB(Bh1, Bm1, 3); SBAR(); CL(Aa, Bh0, Bm0); SBAR();
      RDA6(Aa, 4); RDB(Bh0, Bm0, 4); SBAR(); CL(Ab, Bh1, Bm1); SBAR();
      CL(Aa, Bh0, Bm0);
    } else {         // taps 5..8
      RDA6(Aa, 5); RDB(Bh0, Bm0, 5); SBAR();
      RDA6(Ab, 6); RDB(Bh1, Bm1, 6); SBAR(); CL(Aa, Bh0, Bm0); SBAR();
      RDA6(Aa, 7); RDB(Bh0, Bm0, 7); SBAR(); CL(Ab, Bh1, Bm1); SBAR();
      RDA6(Ab, 8); RDB(Bh1, Bm1, 8); SBAR(); CL(Aa, Bh0, Bm0); SBAR();
      CL(Ab, Bh1, Bm1);
    }
    __syncthreads();
  }

  // epilogue: 4 partials (one per wave) in Lf[4][96][36]; combine+bias+leaky+split
  float* Lf = (float*)smem;
#pragma unroll
  for (int half = 0; half < 2; ++half) {
    if (half == 0) { STO(acc0, 0); STO(acc1, 1); STO(acc2, 2); }
    else           { STO(acc3, 0); STO(acc4, 1); STO(acc5, 2); }
    __syncthreads();
    for (int u = tid; u < 768; u += 256) {
      int pl = u / 384, rem = u - pl*384;
      int gq = rem / 96, lp = rem - gq*96;
      int lpos = half*96 + lp;
      if (lpos < CNT) {
        int p = PB + lpos;
        int pp = p + 2*(p/19) + 22;
        const float* bb = bias + slice*32 + gq*8;
        bf16x8 o;
#pragma unroll
        for (int j = 0; j < 8; ++j) {
          int coix = lp*36 + gq*8 + j;
          float v = Lf[coix] + Lf[3456 + coix] + Lf[6912 + coix] + Lf[10368 + coix] + bb[j];
          v = v > 0.f ? v : 0.1f*v;
          __bf16 hh = (__bf16)v;
          o[j] = pl == 0 ? hh : (__bf16)(v - (float)hh);
        }
        *(bf16x8*)(Xd + (((size_t)pl*16 + b)*64 + slice*4 + gq)*GSTR + (size_t)pp*8) = o;
      }
    }
    __syncthreads();
  }

  // zero output halo rows for this h-half (halo columns are x=0 and x=20)
  const int nh = h ? 39 : 41;
  for (int u = tid; u < 8*nh; u += 256) {
    int pl = u / (4*nh); int rem = u - pl*4*nh;
    int gq = rem / nh; int ci2 = rem - gq*nh;
    int rowpos;
    if (ci2 < 21) rowpos = h ? (420 + ci2) : ci2;
    else { int q = ci2 - 21; rowpos = ((h ? 11 : 1) + (q >> 1))*21 + 20*(q & 1); }
    bf16x8 z = {};
    *(bf16x8*)(Xd + (((size_t)pl*16 + b)*64 + slice*4 + gq)*GSTR + (size_t)rowpos*8) = z;
  }
}

// ---------------- 1x1 heads on split planes ----------------
__global__ __launch_bounds__(256) void head_rf_k(
    const __bf16* __restrict__ F, const float* __restrict__ wobj,
    const float* __restrict__ bobj, const float* __restrict__ wreg,
    const float* __restrict__ breg, float* __restrict__ obj, float* __restrict__ regp)
{
  int gw = blockIdx.x*4 + (threadIdx.x >> 6);
  if (gw >= NB*NPOS) return;
  int lane = threadIdx.x & 63;
  int b = gw / NPOS, p = gw % NPOS;
  int pp = p + 2*(p/19) + 22;
  const __bf16* base = F + (((size_t)b)*64 + lane)*GSTR + (size_t)pp*8;
  bf16x8 v0 = *(const bf16x8*)base;
  bf16x8 v1 = *(const bf16x8*)(base + PLANE);
  float f[8];
#pragma unroll
  for (int j = 0; j < 8; ++j) f[j] = (float)v0[j] + (float)v1[j];
#pragma unroll
  for (int o = 0; o < 5; ++o) {
    const float* wp = (o == 0) ? wobj : wreg + (o-1)*CCH;
    float4 wa = *(const float4*)(wp + lane*8);
    float4 wb = *(const float4*)(wp + lane*8 + 4);
    float s2 = f[0]*wa.x + f[1]*wa.y + f[2]*wa.z + f[3]*wa.w
             + f[4]*wb.x + f[5]*wb.y + f[6]*wb.z + f[7]*wb.w;
#pragma unroll
    for (int d = 32; d; d >>= 1) s2 += __shfl_xor(s2, d);
    if (lane == 0) {
      if (o == 0) obj[gw] = s2 + bobj[0];
      else regp[(size_t)gw*4 + (o-1)] = s2 + breg[o-1];
    }
  }
}

__global__ __launch_bounds__(256) void head_cls_k(
    const __bf16* __restrict__ F, const float* __restrict__ wcls,
    const float* __restrict__ bcls, float* __restrict__ clsp)
{
  int gw = blockIdx.x*4 + (threadIdx.x >> 6);
  if (gw >= NB*NPOS) return;
  int lane = threadIdx.x & 63;
  int b = gw / NPOS, p = gw % NPOS;
  int pp = p + 2*(p/19) + 22;
  const __bf16* base = F + (((size_t)b)*64 + lane)*GSTR + (size_t)pp*8;
  bf16x8 v0 = *(const bf16x8*)base;
  bf16x8 v1 = *(const bf16x8*)(base + PLANE);
  float f[8];
#pragma unroll
  for (int j = 0; j < 8; ++j) f[j] = (float)v0[j] + (float)v1[j];
#pragma unroll
  for (int o = 0; o < NCLS; ++o) {
    const float* wp = wcls + o*CCH;
    float4 wa = *(const float4*)(wp + lane*8);
    float4 wb = *(const float4*)(wp + lane*8 + 4);
    float s2 = f[0]*wa.x + f[1]*wa.y + f[2]*wa.z + f[3]*wa.w
             + f[4]*wb.x + f[5]*wb.y + f[6]*wb.z + f[7]*wb.w;
#pragma unroll
    for (int d = 32; d; d >>= 1) s2 += __shfl_xor(s2, d);
    if (lane == 0) clsp[(size_t)gw*NCLS + o] = s2 + bcls[o];
  }
}

// ---------------- decode boxes + scores + argmax -------------------------
__global__ void decode_k(const float* __restrict__ obj, const float* __restrict__ clsp,
                         const float* __restrict__ regp, float* __restrict__ outb)
{
  int i = blockIdx.x * 256 + threadIdx.x;
  if (i >= NB * NPOS) return;
  int p = i % NPOS;
  float gx = (float)(p % FMPX), gy = (float)(p / FMPX);
  float4 rg = *(const float4*)&regp[(size_t)i * 4];
  float cx = 1.f / (1.f + expf(-rg.x)) + gx;
  float cy = 1.f / (1.f + expf(-rg.y)) + gy;
  float whw = expf(rg.z), whh = expf(rg.w);
  float x1 = fminf(fmaxf((cx - whw * 0.5f) * BSCALE, 0.f), 1.f);
  float y1 = fminf(fmaxf((cy - whh * 0.5f) * BSCALE, 0.f), 1.f);
  float x2 = fminf(fmaxf((cx + whw * 0.5f) * BSCALE, 0.f), 1.f);
  float y2 = fminf(fmaxf((cy + whh * 0.5f) * BSCALE, 0.f), 1.f);
  outb[(size_t)i * 4 + 0] = x1; outb[(size_t)i * 4 + 1] = y1;
  outb[(size_t)i * 4 + 2] = x2; outb[(size_t)i * 4 + 3] = y2;

  float so = 1.f / (1.f + expf(-obj[i]));
  float cv[20];
  const float4* cp = (const float4*)&clsp[(size_t)i * 20];
#pragma unroll
  for (int q = 0; q < 5; q++) {
    float4 v4 = cp[q];
    cv[q * 4] = v4.x; cv[q * 4 + 1] = v4.y; cv[q * 4 + 2] = v4.z; cv[q * 4 + 3] = v4.w;
  }
  float mx = cv[0];
#pragma unroll
  for (int c = 1; c < 20; c++) mx = fmaxf(mx, cv[c]);
  float sum = 0.f;
#pragma unroll
  for (int c = 0; c < 20; c++) { cv[c] = expf(cv[c] - mx); sum += cv[c]; }
  float inv = so / sum;
  float best = -1.f; int bi = 0;
#pragma unroll
  for (int c = 0; c < 20; c++) { float s = cv[c] * inv; if (s > best) { best = s; bi = c; } }
  outb[SC_OFF + i] = best;
  outb[CLS_OFF + i] = (float)bi;
  outb[KEEP_OFF + i] = 0.f;
}

// ---------------- per (batch,class) greedy NMS ----------------------------
__device__ inline unsigned ordf(float f) {
  unsigned u = __float_as_uint(f);
  return (u & 0x80000000u) ? ~u : (u | 0x80000000u);
}

__global__ __launch_bounds__(64) void nms_k(const float* __restrict__ outb, float* __restrict__ keep_out)
{
  int b = blockIdx.x / NCLS, c = blockIdx.x % NCLS;
  int lane = threadIdx.x;
  __shared__ unsigned long long keys[512];
  __shared__ float bx1[384], by1[384], bx2[384], by2[384], bar[384];
  __shared__ unsigned kp[384];
  __shared__ int sj[384];

  for (int i = lane; i < 512; i += 64) {
    unsigned long long key = 0ULL;
    if (i < NPOS) {
      float sc = outb[SC_OFF + b * NPOS + i];
      int ci = (int)outb[CLS_OFF + b * NPOS + i];
      float s = (ci == c && sc >= CONF_T) ? sc : -1.0f;
      key = ((unsigned long long)ordf(s) << 32) | (unsigned)(~(unsigned)i);
    }
    keys[i] = key;
  }
  __syncthreads();
  for (int kk = 2; kk <= 512; kk <<= 1) {
    for (int jj = kk >> 1; jj > 0; jj >>= 1) {
      for (int i = lane; i < 512; i += 64) {
        int l2 = i ^ jj;
        if (l2 > i) {
          unsigned long long a = keys[i], bb2 = keys[l2];
          bool dir = (i & kk) == 0;
          bool sw = dir ? (a < bb2) : (a > bb2);
          if (sw) { keys[i] = bb2; keys[l2] = a; }
        }
      }
      __syncthreads();
    }
  }
  unsigned ordc = ordf(CONF_T);
  int nvalid = 0;
  for (int i = lane; i < 384; i += 64) {
    unsigned long long key = keys[i];
    unsigned hi = (unsigned)(key >> 32);
    int j = (int)(~(unsigned)key);
    bool valid = (key != 0ULL) && (hi >= ordc);
    kp[i] = valid ? 1u : 0u;
    if (valid) {
      const float* bp = &outb[(size_t)(b * NPOS + j) * 4];
      float x1 = bp[0], y1 = bp[1], x2 = bp[2], y2 = bp[3];
      bx1[i] = x1; by1[i] = y1; bx2[i] = x2; by2[i] = y2;
      bar[i] = (x2 - x1) * (y2 - y1);
      sj[i] = j;
    } else { bx1[i] = 0; by1[i] = 0; bx2[i] = 0; by2[i] = 0; bar[i] = 0; sj[i] = 0; }
    nvalid += __popcll(__ballot(valid));
  }
  __syncthreads();
  for (int i = 0; i < nvalid; ++i) {
    if (kp[i]) {
      float x1i = bx1[i], y1i = by1[i], x2i = bx2[i], y2i = by2[i], ai = bar[i];
      for (int j2 = i + 1 + lane; j2 < nvalid; j2 += 64) {
        if (kp[j2]) {
          float ww = fmaxf(1e-28f, fminf(x2i, bx2[j2]) - fmaxf(x1i, bx1[j2]));
          float hh = fmaxf(1e-28f, fminf(y2i, by2[j2]) - fmaxf(y1i, by1[j2]));
          float inter = ww * hh;
          float iou = inter / (ai + bar[j2] - inter + 1e-14f);
          if (iou > NMS_TH) kp[j2] = 0u;
        }
      }
    }
    __syncthreads();
  }
  for (int i = lane; i < 384; i += 64)
    if (kp[i]) keep_out[b * NPOS + sj[i]] = 1.0f;
}

extern "C" void kernel_launch(void* const* d_in, const int* in_sizes, int n_in,
                              void* d_out, int out_size, void* d_ws, size_t ws_size,
                              hipStream_t stream)
{
  const float* x      = (const float*)d_in[0];
  const float* w_cls1 = (const float*)d_in[1];  const float* b_cls1 = (const float*)d_in[2];
  const float* w_cls2 = (const float*)d_in[3];  const float* b_cls2 = (const float*)d_in[4];
  const float* w_reg1 = (const float*)d_in[5];  const float* b_reg1 = (const float*)d_in[6];
  const float* w_reg2 = (const float*)d_in[7];  const float* b_reg2 = (const float*)d_in[8];
  const float* w_reg3 = (const float*)d_in[9];  const float* b_reg3 = (const float*)d_in[10];
  const float* w_reg4 = (const float*)d_in[11]; const float* b_reg4 = (const float*)d_in[12];
  const float* w_obj  = (const float*)d_in[13]; const float* b_obj  = (const float*)d_in[14];
  const float* w_clsh = (const float*)d_in[15]; const float* b_clsh = (const float*)d_in[16];
  const float* w_regh = (const float*)d_in[17]; const float* b_regh = (const float*)d_in[18];
  float* outb = (float*)d_out;

  __bf16* XsA = (__bf16*)d_ws;
  __bf16* XsB = XsA + 2*PLANE;
  __bf16* Wg  = XsB + 2*PLANE;
  float* obj  = (float*)(Wg + (size_t)16*WSL);
  float* regp = obj + NB*NPOS;
  float* clsp = regp + (size_t)NB*NPOS*4;

  auto conv = [&](const float* wsrc, const float* bsrc, const __bf16* src, __bf16* dst) {
    repack_k<<<dim3(16, 32), 256, 0, stream>>>(wsrc, Wg);
    conv3x3_mfma<<<512, 256, 0, stream>>>(src, Wg, bsrc, dst);
  };

  split_x_k<<<dim3(64, NB), 256, 0, stream>>>(x, XsA);
  conv(w_reg1, b_reg1, XsA, XsB);
  conv(w_reg2, b_reg2, XsB, XsA);
  conv(w_reg3, b_reg3, XsA, XsB);
  conv(w_reg4, b_reg4, XsB, XsA);                    // rf = XsA
  head_rf_k<<<1444, 256, 0, stream>>>(XsA, w_obj, b_obj, w_regh, b_regh, obj, regp);
  split_x_k<<<dim3(64, NB), 256, 0, stream>>>(x, XsB);
  conv(w_cls1, b_cls1, XsB, XsA);
  conv(w_cls2, b_cls2, XsA, XsB);                    // cf = XsB
  head_cls_k<<<1444, 256, 0, stream>>>(XsB, w_clsh, b_clsh, clsp);
  decode_k<<<(NB * NPOS + 255) / 256, 256, 0, stream>>>(obj, clsp, regp, outb);
  nms_k<<<NB * NCLS, 64, 0, stream>>>(outb, outb + KEEP_OFF);
}

// Round 9
// 848.217 us; speedup vs baseline: 3.9190x; 1.9917x over previous
//
#include <hip/hip_runtime.h>
#include <hip/hip_bf16.h>
#include <stdint.h>

typedef __bf16 bf16x8 __attribute__((ext_vector_type(8)));
typedef float  f32x16 __attribute__((ext_vector_type(16)));

#define FMPX 19
#define NPOS 361
#define CCH  512
#define NB   16
#define NCLS 20
#define CONF_T 0.001f
#define NMS_TH 0.6f
#define BSCALE (32.0f/608.0f)

#define SC_OFF   (NB*NPOS*4)
#define CLS_OFF  (SC_OFF + NB*NPOS)
#define KEEP_OFF (CLS_OFF + NB*NPOS)

#define GSTR  3528                     // 441 rows * 8 ci elems
#define PLANE ((size_t)3612672)        // 16 b * 64 g * 3528 elems per split plane
#define WSL   294912                   // W elems per slice: 2pl*9t*32ch*512
#define XBUF  16384                    // 2pl * 2kh * 4096B
#define WBUF  18432                    // 2pl * 9tap * 2kh * 32co * 16B
#define WOFF  32768                    // 2*XBUF
#define SMEMB 69632                    // 2*XBUF + 2*WBUF (>= Lf 55296)

__device__ __forceinline__ void gl_lds16(const void* g, void* l) {
  __builtin_amdgcn_global_load_lds(
      (const __attribute__((address_space(1))) unsigned int*)g,
      (__attribute__((address_space(3))) unsigned int*)l, 16, 0, 0);
}
#define MFMA32(A,B,C) __builtin_amdgcn_mfma_f32_32x32x16_bf16(A,B,C,0,0,0)
#define SBAR() __builtin_amdgcn_sched_barrier(0)
#define PRIO1 __builtin_amdgcn_s_setprio(1)
#define PRIO0 __builtin_amdgcn_s_setprio(0)

// tap byte offsets in padded-row LDS (goffs*16)
#define GOF0 (-352)
#define GOF1 (-336)
#define GOF2 (-320)
#define GOF3 (-16)
#define GOF4 (0)
#define GOF5 (16)
#define GOF6 (320)
#define GOF7 (336)
#define GOF8 (352)
#define GO16(T) (GOF##T)

// ---------------- split x: f32 NCHW -> 2 bf16 planes [pl][b][g][row441][8ci]
__global__ void split_x_k(const float* __restrict__ x, __bf16* __restrict__ Xd) {
  __shared__ float sx[8][368];
  int g = blockIdx.x, b = blockIdx.y;
  int tid = threadIdx.x;
  for (int i = tid; i < 8*361; i += 256) {
    int ci = i / 361, p = i - ci*361;
    sx[ci][p] = x[((size_t)b*CCH + g*8 + ci)*NPOS + p];
  }
  __syncthreads();
  for (int row = tid; row < 441; row += 256) {
    int y = row/21, xx = row - y*21;
    bf16x8 oh = {}, om = {};
    if (y >= 1 && y <= 19 && xx >= 1 && xx <= 19) {
      int p = (y-1)*19 + xx - 1;
#pragma unroll
      for (int j = 0; j < 8; ++j) {
        float v = sx[j][p];
        __bf16 hh = (__bf16)v;
        oh[j] = hh; om[j] = (__bf16)(v - (float)hh);
      }
    }
    size_t o = (((size_t)b)*64 + g)*GSTR + (size_t)row*8;
    *(bf16x8*)(Xd + o)         = oh;
    *(bf16x8*)(Xd + PLANE + o) = om;
  }
}

// ---------------- weight repack+split: w[co][ci][3][3] f32 ->
//  Wg [slice16][pl2][tap9][chunk32][kh2][co32][8ci] bf16
__global__ void repack_k(const float* __restrict__ w, __bf16* __restrict__ Wg) {
  __shared__ float sw[32][145];
  int slice = blockIdx.x, chunk = blockIdx.y;
  int tid = threadIdx.x;
  for (int i = tid; i < 32*144; i += 256) {
    int cl = i / 144, r = i - cl*144;
    sw[cl][r] = w[((size_t)slice*32 + cl)*4608 + chunk*144 + r];
  }
  __syncthreads();
  for (int u = tid; u < 1152; u += 256) {
    int co = u & 31, kh = (u >> 5) & 1, pt = u >> 6;   // pt 0..17
    int tap = pt % 9, pl = pt / 9;
    bf16x8 o;
#pragma unroll
    for (int j = 0; j < 8; ++j) {
      float v = sw[co][(kh*8 + j)*9 + tap];
      __bf16 hh = (__bf16)v;
      o[j] = pl == 0 ? hh : (__bf16)(v - (float)hh);
    }
    *(bf16x8*)(Wg + (((size_t)(slice*2 + pl)*9 + tap)*32 + chunk)*512 + kh*256 + co*8) = o;
  }
}

#define RDA6(SP, T) do { \
  SP##0 = *(const bf16x8*)(Xc + aoff0 + GO16(T)); \
  SP##1 = *(const bf16x8*)(Xc + aoff1 + GO16(T)); \
  SP##2 = *(const bf16x8*)(Xc + aoff2 + GO16(T)); \
  SP##3 = *(const bf16x8*)(Xc + aoff3 + GO16(T)); \
  SP##4 = *(const bf16x8*)(Xc + aoff4 + GO16(T)); \
  SP##5 = *(const bf16x8*)(Xc + aoff5 + GO16(T)); } while (0)

#define RDB(BH_, BM_, T) do { \
  BH_ = *(const bf16x8*)(Wc + (T)*1024 + boff); \
  BM_ = *(const bf16x8*)(Wc + 9216 + (T)*1024 + boff); } while (0)

#define CL(SP, BH_, BM_) do { PRIO1; \
  acc0 = MFMA32(SP##0, BH_, acc0); acc1 = MFMA32(SP##1, BH_, acc1); \
  acc2 = MFMA32(SP##2, BH_, acc2); acc3 = MFMA32(SP##3, BH_, acc3); \
  acc4 = MFMA32(SP##4, BH_, acc4); acc5 = MFMA32(SP##5, BH_, acc5); \
  acc0 = MFMA32(SP##0, BM_, acc0); acc1 = MFMA32(SP##1, BM_, acc1); \
  acc2 = MFMA32(SP##2, BM_, acc2); acc3 = MFMA32(SP##3, BM_, acc3); \
  acc4 = MFMA32(SP##4, BM_, acc4); acc5 = MFMA32(SP##5, BM_, acc5); \
  PRIO0; } while (0)

#define STO(A, MTL) do { _Pragma("unroll") \
  for (int r = 0; r < 16; ++r) { \
    Lf[wq*3456 + ((MTL)*32 + 4*kh + (r & 3) + 8*(r >> 2))*36 + col] = (A)[r]; } } while (0)

// ---------------- 3x3 conv: bf16x2, 4 products {hh,hm,mh,mm}
// grid 512 (b,slice,h); block 256 = 4 waves: pg (A-plane h/m) x tg (taps 0-4/5-8)
// wave: 6 m-tiles x 32 co; A and W both LDS-staged (double-buffered), 2 blocks/CU.
// Staging addresses fully inline (no descriptor arrays -> no scratch spill).
__global__ __launch_bounds__(256, 2) void conv3x3_mfma(
    const __bf16* __restrict__ Xs, const __bf16* __restrict__ Wg,
    const float* __restrict__ bias, __bf16* __restrict__ Xd)
{
  __shared__ __attribute__((aligned(16))) char smem[SMEMB];
  const int tid = threadIdx.x;
  const int bid = blockIdx.x;
  const int b = bid & 15, slice = (bid >> 4) & 15, h = bid >> 8;
  const int lane = tid & 63;
  const int wq = __builtin_amdgcn_readfirstlane(tid >> 6);
  const int pg = wq & 1, tg = wq >> 1;
  const int col = lane & 31, kh = lane >> 5;
  const int PB = h*190, CNT = h ? 171 : 190;
  const int PEND = PB + CNT - 1;
  const int clampU = h ? 230 : 251;

  // A LDS byte offsets per m-tile (local padded row * 16), within (pg,kh) slot
  int aoff0, aoff1, aoff2, aoff3, aoff4, aoff5;
  {
    int ao[6];
#pragma unroll
    for (int mt = 0; mt < 6; ++mt) {
      int p = PB + mt*32 + col; if (p > PEND) p = PEND;
      int pp = p + 2*(p/19) + 22;
      ao[mt] = (pp - h*210)*16;
    }
    aoff0 = ao[0]; aoff1 = ao[1]; aoff2 = ao[2];
    aoff3 = ao[3]; aoff4 = ao[4]; aoff5 = ao[5];
  }
  const int boff = kh*512 + col*16;

  // X staging: 4 insts/thread, slot r -> (pl,khs)=(r>>1,r&1), column block j=wq
  int ux = wq*64 + lane; if (ux > clampU) ux = clampU;
  const __bf16* xsb = Xs + (size_t)b*64*GSTR + (size_t)(h*210 + ux)*8;
  // W staging: 5 slots/wave, wk = wq*5+q (skip wk>=18); precomputed scalar offs
  const __bf16* wsb = Wg + (size_t)slice*WSL + (size_t)lane*8;
  int wsrc0, wsrc1, wsrc2, wsrc3, wsrc4;
  int wdst0, wdst1, wdst2, wdst3, wdst4;
  {
    int ws[5], wd[5];
#pragma unroll
    for (int q = 0; q < 5; ++q) {
      int wk = wq*5 + q; if (wk > 17) wk = 17;
      int pl = wk > 8 ? 1 : 0, tap = wk - 9*pl;
      ws[q] = ((pl*9 + tap)*32)*512;
      wd[q] = WOFF + pl*9216 + tap*1024;
    }
    wsrc0 = ws[0]; wsrc1 = ws[1]; wsrc2 = ws[2]; wsrc3 = ws[3]; wsrc4 = ws[4];
    wdst0 = wd[0]; wdst1 = wd[1]; wdst2 = wd[2]; wdst3 = wd[3]; wdst4 = wd[4];
  }
  const bool wv3 = (wq*5 + 3) < 18, wv4 = (wq*5 + 4) < 18;

  auto stage = [&](int c1, int buf) {
    const __bf16* xs = xsb + (size_t)(2*c1)*GSTR;
    char* xd = smem + (buf ? XBUF : 0) + wq*1024;
    gl_lds16(xs,                    xd);
    gl_lds16(xs + GSTR,             xd + 4096);
    gl_lds16(xs + PLANE,            xd + 8192);
    gl_lds16(xs + PLANE + GSTR,     xd + 12288);
    const __bf16* wsc = wsb + (size_t)c1*512;
    char* wb = smem + (buf ? WBUF : 0);
    gl_lds16(wsc + wsrc0, wb + wdst0);
    gl_lds16(wsc + wsrc1, wb + wdst1);
    gl_lds16(wsc + wsrc2, wb + wdst2);
    if (wv3) gl_lds16(wsc + wsrc3, wb + wdst3);
    if (wv4) gl_lds16(wsc + wsrc4, wb + wdst4);
  };

  f32x16 acc0 = {}, acc1 = {}, acc2 = {}, acc3 = {}, acc4 = {}, acc5 = {};

  stage(0, 0);
  __syncthreads();

  for (int c = 0; c < 32; ++c) {
    const char* Xc = smem + (c & 1)*XBUF + pg*8192 + kh*4096;
    const char* Wc = smem + WOFF + (c & 1)*WBUF;
    if (c < 31) stage(c + 1, (c + 1) & 1);

    bf16x8 Aa0, Aa1, Aa2, Aa3, Aa4, Aa5, Ab0, Ab1, Ab2, Ab3, Ab4, Ab5;
    bf16x8 Bh0, Bm0, Bh1, Bm1;
    if (tg == 0) {   // taps 0..4
      RDA6(Aa, 0); RDB(Bh0, Bm0, 0); SBAR();
      RDA6(Ab, 1); RDB(Bh1, Bm1, 1); SBAR(); CL(Aa, Bh0, Bm0); SBAR();
      RDA6(Aa, 2); RDB(Bh0, Bm0, 2); SBAR(); CL(Ab, Bh1, Bm1); SBAR();
      RDA6(Ab, 3); RDB(Bh1, Bm1, 3); SBAR(); CL(Aa, Bh0, Bm0); SBAR();
      RDA6(Aa, 4); RDB(Bh0, Bm0, 4); SBAR(); CL(Ab, Bh1, Bm1); SBAR();
      CL(Aa, Bh0, Bm0);
    } else {         // taps 5..8
      RDA6(Aa, 5); RDB(Bh0, Bm0, 5); SBAR();
      RDA6(Ab, 6); RDB(Bh1, Bm1, 6); SBAR(); CL(Aa, Bh0, Bm0); SBAR();
      RDA6(Aa, 7); RDB(Bh0, Bm0, 7); SBAR(); CL(Ab, Bh1, Bm1); SBAR();
      RDA6(Ab, 8); RDB(Bh1, Bm1, 8); SBAR(); CL(Aa, Bh0, Bm0); SBAR();
      CL(Ab, Bh1, Bm1);
    }
    __syncthreads();
  }

  // epilogue: 4 partials (one per wave) in Lf[4][96][36]; combine+bias+leaky+split
  float* Lf = (float*)smem;
#pragma unroll
  for (int half = 0; half < 2; ++half) {
    if (half == 0) { STO(acc0, 0); STO(acc1, 1); STO(acc2, 2); }
    else           { STO(acc3, 0); STO(acc4, 1); STO(acc5, 2); }
    __syncthreads();
    for (int u = tid; u < 768; u += 256) {
      int pl = u / 384, rem = u - pl*384;
      int gq = rem / 96, lp = rem - gq*96;
      int lpos = half*96 + lp;
      if (lpos < CNT) {
        int p = PB + lpos;
        int pp = p + 2*(p/19) + 22;
        const float* bb = bias + slice*32 + gq*8;
        bf16x8 o;
#pragma unroll
        for (int j = 0; j < 8; ++j) {
          int coix = lp*36 + gq*8 + j;
          float v = Lf[coix] + Lf[3456 + coix] + Lf[6912 + coix] + Lf[10368 + coix] + bb[j];
          v = v > 0.f ? v : 0.1f*v;
          __bf16 hh = (__bf16)v;
          o[j] = pl == 0 ? hh : (__bf16)(v - (float)hh);
        }
        *(bf16x8*)(Xd + (((size_t)pl*16 + b)*64 + slice*4 + gq)*GSTR + (size_t)pp*8) = o;
      }
    }
    __syncthreads();
  }

  // zero output halo rows for this h-half (halo columns are x=0 and x=20)
  const int nh = h ? 39 : 41;
  for (int u = tid; u < 8*nh; u += 256) {
    int pl = u / (4*nh); int rem = u - pl*4*nh;
    int gq = rem / nh; int ci2 = rem - gq*nh;
    int rowpos;
    if (ci2 < 21) rowpos = h ? (420 + ci2) : ci2;
    else { int q = ci2 - 21; rowpos = ((h ? 11 : 1) + (q >> 1))*21 + 20*(q & 1); }
    bf16x8 z = {};
    *(bf16x8*)(Xd + (((size_t)pl*16 + b)*64 + slice*4 + gq)*GSTR + (size_t)rowpos*8) = z;
  }
}

// ---------------- 1x1 heads on split planes ----------------
__global__ __launch_bounds__(256) void head_rf_k(
    const __bf16* __restrict__ F, const float* __restrict__ wobj,
    const float* __restrict__ bobj, const float* __restrict__ wreg,
    const float* __restrict__ breg, float* __restrict__ obj, float* __restrict__ regp)
{
  int gw = blockIdx.x*4 + (threadIdx.x >> 6);
  if (gw >= NB*NPOS) return;
  int lane = threadIdx.x & 63;
  int b = gw / NPOS, p = gw % NPOS;
  int pp = p + 2*(p/19) + 22;
  const __bf16* base = F + (((size_t)b)*64 + lane)*GSTR + (size_t)pp*8;
  bf16x8 v0 = *(const bf16x8*)base;
  bf16x8 v1 = *(const bf16x8*)(base + PLANE);
  float f[8];
#pragma unroll
  for (int j = 0; j < 8; ++j) f[j] = (float)v0[j] + (float)v1[j];
#pragma unroll
  for (int o = 0; o < 5; ++o) {
    const float* wp = (o == 0) ? wobj : wreg + (o-1)*CCH;
    float4 wa = *(const float4*)(wp + lane*8);
    float4 wb = *(const float4*)(wp + lane*8 + 4);
    float s2 = f[0]*wa.x + f[1]*wa.y + f[2]*wa.z + f[3]*wa.w
             + f[4]*wb.x + f[5]*wb.y + f[6]*wb.z + f[7]*wb.w;
#pragma unroll
    for (int d = 32; d; d >>= 1) s2 += __shfl_xor(s2, d);
    if (lane == 0) {
      if (o == 0) obj[gw] = s2 + bobj[0];
      else regp[(size_t)gw*4 + (o-1)] = s2 + breg[o-1];
    }
  }
}

__global__ __launch_bounds__(256) void head_cls_k(
    const __bf16* __restrict__ F, const float* __restrict__ wcls,
    const float* __restrict__ bcls, float* __restrict__ clsp)
{
  int gw = blockIdx.x*4 + (threadIdx.x >> 6);
  if (gw >= NB*NPOS) return;
  int lane = threadIdx.x & 63;
  int b = gw / NPOS, p = gw % NPOS;
  int pp = p + 2*(p/19) + 22;
  const __bf16* base = F + (((size_t)b)*64 + lane)*GSTR + (size_t)pp*8;
  bf16x8 v0 = *(const bf16x8*)base;
  bf16x8 v1 = *(const bf16x8*)(base + PLANE);
  float f[8];
#pragma unroll
  for (int j = 0; j < 8; ++j) f[j] = (float)v0[j] + (float)v1[j];
#pragma unroll
  for (int o = 0; o < NCLS; ++o) {
    const float* wp = wcls + o*CCH;
    float4 wa = *(const float4*)(wp + lane*8);
    float4 wb = *(const float4*)(wp + lane*8 + 4);
    float s2 = f[0]*wa.x + f[1]*wa.y + f[2]*wa.z + f[3]*wa.w
             + f[4]*wb.x + f[5]*wb.y + f[6]*wb.z + f[7]*wb.w;
#pragma unroll
    for (int d = 32; d; d >>= 1) s2 += __shfl_xor(s2, d);
    if (lane == 0) clsp[(size_t)gw*NCLS + o] = s2 + bcls[o];
  }
}

// ---------------- decode boxes + scores + argmax -------------------------
__global__ void decode_k(const float* __restrict__ obj, const float* __restrict__ clsp,
                         const float* __restrict__ regp, float* __restrict__ outb)
{
  int i = blockIdx.x * 256 + threadIdx.x;
  if (i >= NB * NPOS) return;
  int p = i % NPOS;
  float gx = (float)(p % FMPX), gy = (float)(p / FMPX);
  float4 rg = *(const float4*)&regp[(size_t)i * 4];
  float cx = 1.f / (1.f + expf(-rg.x)) + gx;
  float cy = 1.f / (1.f + expf(-rg.y)) + gy;
  float whw = expf(rg.z), whh = expf(rg.w);
  float x1 = fminf(fmaxf((cx - whw * 0.5f) * BSCALE, 0.f), 1.f);
  float y1 = fminf(fmaxf((cy - whh * 0.5f) * BSCALE, 0.f), 1.f);
  float x2 = fminf(fmaxf((cx + whw * 0.5f) * BSCALE, 0.f), 1.f);
  float y2 = fminf(fmaxf((cy + whh * 0.5f) * BSCALE, 0.f), 1.f);
  outb[(size_t)i * 4 + 0] = x1; outb[(size_t)i * 4 + 1] = y1;
  outb[(size_t)i * 4 + 2] = x2; outb[(size_t)i * 4 + 3] = y2;

  float so = 1.f / (1.f + expf(-obj[i]));
  float cv[20];
  const float4* cp = (const float4*)&clsp[(size_t)i * 20];
#pragma unroll
  for (int q = 0; q < 5; q++) {
    float4 v4 = cp[q];
    cv[q * 4] = v4.x; cv[q * 4 + 1] = v4.y; cv[q * 4 + 2] = v4.z; cv[q * 4 + 3] = v4.w;
  }
  float mx = cv[0];
#pragma unroll
  for (int c = 1; c < 20; c++) mx = fmaxf(mx, cv[c]);
  float sum = 0.f;
#pragma unroll
  for (int c = 0; c < 20; c++) { cv[c] = expf(cv[c] - mx); sum += cv[c]; }
  float inv = so / sum;
  float best = -1.f; int bi = 0;
#pragma unroll
  for (int c = 0; c < 20; c++) { float s = cv[c] * inv; if (s > best) { best = s; bi = c; } }
  outb[SC_OFF + i] = best;
  outb[CLS_OFF + i] = (float)bi;
  outb[KEEP_OFF + i] = 0.f;
}

// ---------------- per (batch,class) greedy NMS ----------------------------
__device__ inline unsigned ordf(float f) {
  unsigned u = __float_as_uint(f);
  return (u & 0x80000000u) ? ~u : (u | 0x80000000u);
}

__global__ __launch_bounds__(64) void nms_k(const float* __restrict__ outb, float* __restrict__ keep_out)
{
  int b = blockIdx.x / NCLS, c = blockIdx.x % NCLS;
  int lane = threadIdx.x;
  __shared__ unsigned long long keys[512];
  __shared__ float bx1[384], by1[384], bx2[384], by2[384], bar[384];
  __shared__ unsigned kp[384];
  __shared__ int sj[384];

  for (int i = lane; i < 512; i += 64) {
    unsigned long long key = 0ULL;
    if (i < NPOS) {
      float sc = outb[SC_OFF + b * NPOS + i];
      int ci = (int)outb[CLS_OFF + b * NPOS + i];
      float s = (ci == c && sc >= CONF_T) ? sc : -1.0f;
      key = ((unsigned long long)ordf(s) << 32) | (unsigned)(~(unsigned)i);
    }
    keys[i] = key;
  }
  __syncthreads();
  for (int kk = 2; kk <= 512; kk <<= 1) {
    for (int jj = kk >> 1; jj > 0; jj >>= 1) {
      for (int i = lane; i < 512; i += 64) {
        int l2 = i ^ jj;
        if (l2 > i) {
          unsigned long long a = keys[i], bb2 = keys[l2];
          bool dir = (i & kk) == 0;
          bool sw = dir ? (a < bb2) : (a > bb2);
          if (sw) { keys[i] = bb2; keys[l2] = a; }
        }
      }
      __syncthreads();
    }
  }
  unsigned ordc = ordf(CONF_T);
  int nvalid = 0;
  for (int i = lane; i < 384; i += 64) {
    unsigned long long key = keys[i];
    unsigned hi = (unsigned)(key >> 32);
    int j = (int)(~(unsigned)key);
    bool valid = (key != 0ULL) && (hi >= ordc);
    kp[i] = valid ? 1u : 0u;
    if (valid) {
      const float* bp = &outb[(size_t)(b * NPOS + j) * 4];
      float x1 = bp[0], y1 = bp[1], x2 = bp[2], y2 = bp[3];
      bx1[i] = x1; by1[i] = y1; bx2[i] = x2; by2[i] = y2;
      bar[i] = (x2 - x1) * (y2 - y1);
      sj[i] = j;
    } else { bx1[i] = 0; by1[i] = 0; bx2[i] = 0; by2[i] = 0; bar[i] = 0; sj[i] = 0; }
    nvalid += __popcll(__ballot(valid));
  }
  __syncthreads();
  for (int i = 0; i < nvalid; ++i) {
    if (kp[i]) {
      float x1i = bx1[i], y1i = by1[i], x2i = bx2[i], y2i = by2[i], ai = bar[i];
      for (int j2 = i + 1 + lane; j2 < nvalid; j2 += 64) {
        if (kp[j2]) {
          float ww = fmaxf(1e-28f, fminf(x2i, bx2[j2]) - fmaxf(x1i, bx1[j2]));
          float hh = fmaxf(1e-28f, fminf(y2i, by2[j2]) - fmaxf(y1i, by1[j2]));
          float inter = ww * hh;
          float iou = inter / (ai + bar[j2] - inter + 1e-14f);
          if (iou > NMS_TH) kp[j2] = 0u;
        }
      }
    }
    __syncthreads();
  }
  for (int i = lane; i < 384; i += 64)
    if (kp[i]) keep_out[b * NPOS + sj[i]] = 1.0f;
}

extern "C" void kernel_launch(void* const* d_in, const int* in_sizes, int n_in,
                              void* d_out, int out_size, void* d_ws, size_t ws_size,
                              hipStream_t stream)
{
  const float* x      = (const float*)d_in[0];
  const float* w_cls1 = (const float*)d_in[1];  const float* b_cls1 = (const float*)d_in[2];
  const float* w_cls2 = (const float*)d_in[3];  const float* b_cls2 = (const float*)d_in[4];
  const float* w_reg1 = (const float*)d_in[5];  const float* b_reg1 = (const float*)d_in[6];
  const float* w_reg2 = (const float*)d_in[7];  const float* b_reg2 = (const float*)d_in[8];
  const float* w_reg3 = (const float*)d_in[9];  const float* b_reg3 = (const float*)d_in[10];
  const float* w_reg4 = (const float*)d_in[11]; const float* b_reg4 = (const float*)d_in[12];
  const float* w_obj  = (const float*)d_in[13]; const float* b_obj  = (const float*)d_in[14];
  const float* w_clsh = (const float*)d_in[15]; const float* b_clsh = (const float*)d_in[16];
  const float* w_regh = (const float*)d_in[17]; const float* b_regh = (const float*)d_in[18];
  float* outb = (float*)d_out;

  __bf16* XsA = (__bf16*)d_ws;
  __bf16* XsB = XsA + 2*PLANE;
  __bf16* Wg  = XsB + 2*PLANE;
  float* obj  = (float*)(Wg + (size_t)16*WSL);
  float* regp = obj + NB*NPOS;
  float* clsp = regp + (size_t)NB*NPOS*4;

  auto conv = [&](const float* wsrc, const float* bsrc, const __bf16* src, __bf16* dst) {
    repack_k<<<dim3(16, 32), 256, 0, stream>>>(wsrc, Wg);
    conv3x3_mfma<<<512, 256, 0, stream>>>(src, Wg, bsrc, dst);
  };

  split_x_k<<<dim3(64, NB), 256, 0, stream>>>(x, XsA);
  conv(w_reg1, b_reg1, XsA, XsB);
  conv(w_reg2, b_reg2, XsB, XsA);
  conv(w_reg3, b_reg3, XsA, XsB);
  conv(w_reg4, b_reg4, XsB, XsA);                    // rf = XsA
  head_rf_k<<<1444, 256, 0, stream>>>(XsA, w_obj, b_obj, w_regh, b_regh, obj, regp);
  split_x_k<<<dim3(64, NB), 256, 0, stream>>>(x, XsB);
  conv(w_cls1, b_cls1, XsB, XsA);
  conv(w_cls2, b_cls2, XsA, XsB);                    // cf = XsB
  head_cls_k<<<1444, 256, 0, stream>>>(XsB, w_clsh, b_clsh, clsp);
  decode_k<<<(NB * NPOS + 255) / 256, 256, 0, stream>>>(obj, clsp, regp, outb);
  nms_k<<<NB * NCLS, 64, 0, stream>>>(outb, outb + KEEP_OFF);
}

// Round 10
// 836.123 us; speedup vs baseline: 3.9757x; 1.0145x over previous
//
#include <hip/hip_runtime.h>
#include <hip/hip_bf16.h>
#include <stdint.h>

typedef __bf16 bf16x8 __attribute__((ext_vector_type(8)));
typedef float  f32x16 __attribute__((ext_vector_type(16)));

#define FMPX 19
#define NPOS 361
#define CCH  512
#define NB   16
#define NCLS 20
#define CONF_T 0.001f
#define NMS_TH 0.6f
#define BSCALE (32.0f/608.0f)

#define SC_OFF   (NB*NPOS*4)
#define CLS_OFF  (SC_OFF + NB*NPOS)
#define KEEP_OFF (CLS_OFF + NB*NPOS)

#define GSTR  3528                     // 441 rows * 8 ci elems
#define PLANE ((size_t)3612672)        // 16 b * 64 g * 3528 elems per split plane
#define WSL   294912                   // W elems per slice: 2pl*9t*32ch*512
#define XBUF  16384                    // 2pl * 2kh * 4096B
#define WBUF  18432                    // 2pl * 9tap * 2kh * 32co * 16B
#define WOFF  32768                    // 2*XBUF
#define SMEMB 69632                    // 2*XBUF + 2*WBUF (>= Lf 55296)

__device__ __forceinline__ void gl_lds16(const void* g, void* l) {
  __builtin_amdgcn_global_load_lds(
      (const __attribute__((address_space(1))) unsigned int*)g,
      (__attribute__((address_space(3))) unsigned int*)l, 16, 0, 0);
}
#define MFMA32(A,B,C) __builtin_amdgcn_mfma_f32_32x32x16_bf16(A,B,C,0,0,0)
#define SBAR() __builtin_amdgcn_sched_barrier(0)
#define PRIO1 __builtin_amdgcn_s_setprio(1)
#define PRIO0 __builtin_amdgcn_s_setprio(0)

// tap byte offsets in padded-row LDS (goffs*16)
#define GOF0 (-352)
#define GOF1 (-336)
#define GOF2 (-320)
#define GOF3 (-16)
#define GOF4 (0)
#define GOF5 (16)
#define GOF6 (320)
#define GOF7 (336)
#define GOF8 (352)
#define GO16(T) (GOF##T)

// ---------------- split x: f32 NCHW -> 2 bf16 planes [pl][b][g][row441][8ci]
__global__ void split_x_k(const float* __restrict__ x, __bf16* __restrict__ Xd) {
  __shared__ float sx[8][368];
  int g = blockIdx.x, b = blockIdx.y;
  int tid = threadIdx.x;
  for (int i = tid; i < 8*361; i += 256) {
    int ci = i / 361, p = i - ci*361;
    sx[ci][p] = x[((size_t)b*CCH + g*8 + ci)*NPOS + p];
  }
  __syncthreads();
  for (int row = tid; row < 441; row += 256) {
    int y = row/21, xx = row - y*21;
    bf16x8 oh = {}, om = {};
    if (y >= 1 && y <= 19 && xx >= 1 && xx <= 19) {
      int p = (y-1)*19 + xx - 1;
#pragma unroll
      for (int j = 0; j < 8; ++j) {
        float v = sx[j][p];
        __bf16 hh = (__bf16)v;
        oh[j] = hh; om[j] = (__bf16)(v - (float)hh);
      }
    }
    size_t o = (((size_t)b)*64 + g)*GSTR + (size_t)row*8;
    *(bf16x8*)(Xd + o)         = oh;
    *(bf16x8*)(Xd + PLANE + o) = om;
  }
}

// ---------------- weight repack+split: w[co][ci][3][3] f32 ->
//  Wg [slice16][pl2][tap9][chunk32][kh2][co32][8ci] bf16
__global__ void repack_k(const float* __restrict__ w, __bf16* __restrict__ Wg) {
  __shared__ float sw[32][145];
  int slice = blockIdx.x, chunk = blockIdx.y;
  int tid = threadIdx.x;
  for (int i = tid; i < 32*144; i += 256) {
    int cl = i / 144, r = i - cl*144;
    sw[cl][r] = w[((size_t)slice*32 + cl)*4608 + chunk*144 + r];
  }
  __syncthreads();
  for (int u = tid; u < 1152; u += 256) {
    int co = u & 31, kh = (u >> 5) & 1, pt = u >> 6;   // pt 0..17
    int tap = pt % 9, pl = pt / 9;
    bf16x8 o;
#pragma unroll
    for (int j = 0; j < 8; ++j) {
      float v = sw[co][(kh*8 + j)*9 + tap];
      __bf16 hh = (__bf16)v;
      o[j] = pl == 0 ? hh : (__bf16)(v - (float)hh);
    }
    *(bf16x8*)(Wg + (((size_t)(slice*2 + pl)*9 + tap)*32 + chunk)*512 + kh*256 + co*8) = o;
  }
}

#define RDA6(SP, T) do { \
  SP##0 = *(const bf16x8*)(Xc + aoff0 + GO16(T)); \
  SP##1 = *(const bf16x8*)(Xc + aoff1 + GO16(T)); \
  SP##2 = *(const bf16x8*)(Xc + aoff2 + GO16(T)); \
  SP##3 = *(const bf16x8*)(Xc + aoff3 + GO16(T)); \
  SP##4 = *(const bf16x8*)(Xc + aoff4 + GO16(T)); \
  SP##5 = *(const bf16x8*)(Xc + aoff5 + GO16(T)); } while (0)

#define RDB(BH_, BM_, T) do { \
  BH_ = *(const bf16x8*)(Wc + (T)*1024 + boff); \
  BM_ = *(const bf16x8*)(Wc + 9216 + (T)*1024 + boff); } while (0)

#define CL(SP, BH_, BM_) do { PRIO1; \
  acc0 = MFMA32(SP##0, BH_, acc0); acc1 = MFMA32(SP##1, BH_, acc1); \
  acc2 = MFMA32(SP##2, BH_, acc2); acc3 = MFMA32(SP##3, BH_, acc3); \
  acc4 = MFMA32(SP##4, BH_, acc4); acc5 = MFMA32(SP##5, BH_, acc5); \
  acc0 = MFMA32(SP##0, BM_, acc0); acc1 = MFMA32(SP##1, BM_, acc1); \
  acc2 = MFMA32(SP##2, BM_, acc2); acc3 = MFMA32(SP##3, BM_, acc3); \
  acc4 = MFMA32(SP##4, BM_, acc4); acc5 = MFMA32(SP##5, BM_, acc5); \
  PRIO0; } while (0)

#define CLH(SP, B_) do { PRIO1; \
  acc0 = MFMA32(SP##0, B_, acc0); acc1 = MFMA32(SP##1, B_, acc1); \
  acc2 = MFMA32(SP##2, B_, acc2); acc3 = MFMA32(SP##3, B_, acc3); \
  acc4 = MFMA32(SP##4, B_, acc4); acc5 = MFMA32(SP##5, B_, acc5); \
  PRIO0; } while (0)

#define STO(A, MTL) do { _Pragma("unroll") \
  for (int r = 0; r < 16; ++r) { \
    Lf[wq*3456 + ((MTL)*32 + 4*kh + (r & 3) + 8*(r >> 2))*36 + col] = (A)[r]; } } while (0)

// ---------------- 3x3 conv: bf16x2, 4 products {hh,hm,mh,mm}
// grid 512 (b,slice,h); block 256 = 4 waves: pg (A-plane h/m) x tg (tap group)
// Tap 4 is split BY PRODUCT between tg0/tg1 so both roles do exactly 54
// MFMA/chunk (was 60/48 -> 25% barrier skew).
__global__ __launch_bounds__(256, 2) void conv3x3_mfma(
    const __bf16* __restrict__ Xs, const __bf16* __restrict__ Wg,
    const float* __restrict__ bias, __bf16* __restrict__ Xd)
{
  __shared__ __attribute__((aligned(16))) char smem[SMEMB];
  const int tid = threadIdx.x;
  const int bid = blockIdx.x;
  const int b = bid & 15, slice = (bid >> 4) & 15, h = bid >> 8;
  const int lane = tid & 63;
  const int wq = __builtin_amdgcn_readfirstlane(tid >> 6);
  const int pg = wq & 1, tg = wq >> 1;
  const int col = lane & 31, kh = lane >> 5;
  const int PB = h*190, CNT = h ? 171 : 190;
  const int PEND = PB + CNT - 1;
  const int clampU = h ? 230 : 251;

  // A LDS byte offsets per m-tile (local padded row * 16), within (pg,kh) slot
  int aoff0, aoff1, aoff2, aoff3, aoff4, aoff5;
  {
    int ao[6];
#pragma unroll
    for (int mt = 0; mt < 6; ++mt) {
      int p = PB + mt*32 + col; if (p > PEND) p = PEND;
      int pp = p + 2*(p/19) + 22;
      ao[mt] = (pp - h*210)*16;
    }
    aoff0 = ao[0]; aoff1 = ao[1]; aoff2 = ao[2];
    aoff3 = ao[3]; aoff4 = ao[4]; aoff5 = ao[5];
  }
  const int boff = kh*512 + col*16;

  // X staging: 4 insts/thread, slot r -> (pl,khs)=(r>>1,r&1), column block j=wq
  int ux = wq*64 + lane; if (ux > clampU) ux = clampU;
  const __bf16* xsb = Xs + (size_t)b*64*GSTR + (size_t)(h*210 + ux)*8;
  // W staging: 5 slots/wave, wk = wq*5+q (skip wk>=18); precomputed scalar offs
  const __bf16* wsb = Wg + (size_t)slice*WSL + (size_t)lane*8;
  int wsrc0, wsrc1, wsrc2, wsrc3, wsrc4;
  int wdst0, wdst1, wdst2, wdst3, wdst4;
  {
    int ws[5], wd[5];
#pragma unroll
    for (int q = 0; q < 5; ++q) {
      int wk = wq*5 + q; if (wk > 17) wk = 17;
      int pl = wk > 8 ? 1 : 0, tap = wk - 9*pl;
      ws[q] = ((pl*9 + tap)*32)*512;
      wd[q] = WOFF + pl*9216 + tap*1024;
    }
    wsrc0 = ws[0]; wsrc1 = ws[1]; wsrc2 = ws[2]; wsrc3 = ws[3]; wsrc4 = ws[4];
    wdst0 = wd[0]; wdst1 = wd[1]; wdst2 = wd[2]; wdst3 = wd[3]; wdst4 = wd[4];
  }
  const bool wv3 = (wq*5 + 3) < 18, wv4 = (wq*5 + 4) < 18;

  auto stage = [&](int c1, int buf) {
    const __bf16* xs = xsb + (size_t)(2*c1)*GSTR;
    char* xd = smem + (buf ? XBUF : 0) + wq*1024;
    gl_lds16(xs,                    xd);
    gl_lds16(xs + GSTR,             xd + 4096);
    gl_lds16(xs + PLANE,            xd + 8192);
    gl_lds16(xs + PLANE + GSTR,     xd + 12288);
    const __bf16* wsc = wsb + (size_t)c1*512;
    char* wb = smem + (buf ? WBUF : 0);
    gl_lds16(wsc + wsrc0, wb + wdst0);
    gl_lds16(wsc + wsrc1, wb + wdst1);
    gl_lds16(wsc + wsrc2, wb + wdst2);
    if (wv3) gl_lds16(wsc + wsrc3, wb + wdst3);
    if (wv4) gl_lds16(wsc + wsrc4, wb + wdst4);
  };

  f32x16 acc0 = {}, acc1 = {}, acc2 = {}, acc3 = {}, acc4 = {}, acc5 = {};

  stage(0, 0);
  __syncthreads();

  for (int c = 0; c < 32; ++c) {
    const char* Xc = smem + (c & 1)*XBUF + pg*8192 + kh*4096;
    const char* Wc = smem + WOFF + (c & 1)*WBUF;
    if (c < 31) stage(c + 1, (c + 1) & 1);

    bf16x8 Aa0, Aa1, Aa2, Aa3, Aa4, Aa5, Ab0, Ab1, Ab2, Ab3, Ab4, Ab5;
    bf16x8 Bh0, Bm0, Bh1, Bm1;
    if (tg == 0) {   // taps 0..3 full + tap 4 product0 (Bh)
      RDA6(Aa, 0); RDB(Bh0, Bm0, 0); SBAR();
      RDA6(Ab, 1); RDB(Bh1, Bm1, 1); SBAR(); CL(Aa, Bh0, Bm0); SBAR();
      RDA6(Aa, 2); RDB(Bh0, Bm0, 2); SBAR(); CL(Ab, Bh1, Bm1); SBAR();
      RDA6(Ab, 3); RDB(Bh1, Bm1, 3); SBAR(); CL(Aa, Bh0, Bm0); SBAR();
      RDA6(Aa, 4); Bh0 = *(const bf16x8*)(Wc + 4*1024 + boff);
      SBAR(); CL(Ab, Bh1, Bm1); SBAR();
      CLH(Aa, Bh0);
    } else {         // taps 5..8 full + tap 4 product1 (Bm)
      RDA6(Aa, 5); RDB(Bh0, Bm0, 5); SBAR();
      RDA6(Ab, 6); RDB(Bh1, Bm1, 6); SBAR(); CL(Aa, Bh0, Bm0); SBAR();
      RDA6(Aa, 7); RDB(Bh0, Bm0, 7); SBAR(); CL(Ab, Bh1, Bm1); SBAR();
      RDA6(Ab, 8); RDB(Bh1, Bm1, 8); SBAR(); CL(Aa, Bh0, Bm0); SBAR();
      RDA6(Aa, 4); Bm0 = *(const bf16x8*)(Wc + 9216 + 4*1024 + boff);
      SBAR(); CL(Ab, Bh1, Bm1); SBAR();
      CLH(Aa, Bm0);
    }
    __syncthreads();
  }

  // epilogue: 4 partials (one per wave) in Lf[4][96][36]; combine+bias+leaky+split
  float* Lf = (float*)smem;
#pragma unroll
  for (int half = 0; half < 2; ++half) {
    if (half == 0) { STO(acc0, 0); STO(acc1, 1); STO(acc2, 2); }
    else           { STO(acc3, 0); STO(acc4, 1); STO(acc5, 2); }
    __syncthreads();
    for (int u = tid; u < 768; u += 256) {
      int pl = u / 384, rem = u - pl*384;
      int gq = rem / 96, lp = rem - gq*96;
      int lpos = half*96 + lp;
      if (lpos < CNT) {
        int p = PB + lpos;
        int pp = p + 2*(p/19) + 22;
        const float* bb = bias + slice*32 + gq*8;
        bf16x8 o;
#pragma unroll
        for (int j = 0; j < 8; ++j) {
          int coix = lp*36 + gq*8 + j;
          float v = Lf[coix] + Lf[3456 + coix] + Lf[6912 + coix] + Lf[10368 + coix] + bb[j];
          v = v > 0.f ? v : 0.1f*v;
          __bf16 hh = (__bf16)v;
          o[j] = pl == 0 ? hh : (__bf16)(v - (float)hh);
        }
        *(bf16x8*)(Xd + (((size_t)pl*16 + b)*64 + slice*4 + gq)*GSTR + (size_t)pp*8) = o;
      }
    }
    __syncthreads();
  }

  // zero output halo rows for this h-half (halo columns are x=0 and x=20)
  const int nh = h ? 39 : 41;
  for (int u = tid; u < 8*nh; u += 256) {
    int pl = u / (4*nh); int rem = u - pl*4*nh;
    int gq = rem / nh; int ci2 = rem - gq*nh;
    int rowpos;
    if (ci2 < 21) rowpos = h ? (420 + ci2) : ci2;
    else { int q = ci2 - 21; rowpos = ((h ? 11 : 1) + (q >> 1))*21 + 20*(q & 1); }
    bf16x8 z = {};
    *(bf16x8*)(Xd + (((size_t)pl*16 + b)*64 + slice*4 + gq)*GSTR + (size_t)rowpos*8) = z;
  }
}

// ---------------- 1x1 heads on split planes ----------------
__global__ __launch_bounds__(256) void head_rf_k(
    const __bf16* __restrict__ F, const float* __restrict__ wobj,
    const float* __restrict__ bobj, const float* __restrict__ wreg,
    const float* __restrict__ breg, float* __restrict__ obj, float* __restrict__ regp)
{
  int gw = blockIdx.x*4 + (threadIdx.x >> 6);
  if (gw >= NB*NPOS) return;
  int lane = threadIdx.x & 63;
  int b = gw / NPOS, p = gw % NPOS;
  int pp = p + 2*(p/19) + 22;
  const __bf16* base = F + (((size_t)b)*64 + lane)*GSTR + (size_t)pp*8;
  bf16x8 v0 = *(const bf16x8*)base;
  bf16x8 v1 = *(const bf16x8*)(base + PLANE);
  float f[8];
#pragma unroll
  for (int j = 0; j < 8; ++j) f[j] = (float)v0[j] + (float)v1[j];
#pragma unroll
  for (int o = 0; o < 5; ++o) {
    const float* wp = (o == 0) ? wobj : wreg + (o-1)*CCH;
    float4 wa = *(const float4*)(wp + lane*8);
    float4 wb = *(const float4*)(wp + lane*8 + 4);
    float s2 = f[0]*wa.x + f[1]*wa.y + f[2]*wa.z + f[3]*wa.w
             + f[4]*wb.x + f[5]*wb.y + f[6]*wb.z + f[7]*wb.w;
#pragma unroll
    for (int d = 32; d; d >>= 1) s2 += __shfl_xor(s2, d);
    if (lane == 0) {
      if (o == 0) obj[gw] = s2 + bobj[0];
      else regp[(size_t)gw*4 + (o-1)] = s2 + breg[o-1];
    }
  }
}

__global__ __launch_bounds__(256) void head_cls_k(
    const __bf16* __restrict__ F, const float* __restrict__ wcls,
    const float* __restrict__ bcls, float* __restrict__ clsp)
{
  int gw = blockIdx.x*4 + (threadIdx.x >> 6);
  if (gw >= NB*NPOS) return;
  int lane = threadIdx.x & 63;
  int b = gw / NPOS, p = gw % NPOS;
  int pp = p + 2*(p/19) + 22;
  const __bf16* base = F + (((size_t)b)*64 + lane)*GSTR + (size_t)pp*8;
  bf16x8 v0 = *(const bf16x8*)base;
  bf16x8 v1 = *(const bf16x8*)(base + PLANE);
  float f[8];
#pragma unroll
  for (int j = 0; j < 8; ++j) f[j] = (float)v0[j] + (float)v1[j];
#pragma unroll
  for (int o = 0; o < NCLS; ++o) {
    const float* wp = wcls + o*CCH;
    float4 wa = *(const float4*)(wp + lane*8);
    float4 wb = *(const float4*)(wp + lane*8 + 4);
    float s2 = f[0]*wa.x + f[1]*wa.y + f[2]*wa.z + f[3]*wa.w
             + f[4]*wb.x + f[5]*wb.y + f[6]*wb.z + f[7]*wb.w;
#pragma unroll
    for (int d = 32; d; d >>= 1) s2 += __shfl_xor(s2, d);
    if (lane == 0) clsp[(size_t)gw*NCLS + o] = s2 + bcls[o];
  }
}

// ---------------- decode boxes + scores + argmax -------------------------
__global__ void decode_k(const float* __restrict__ obj, const float* __restrict__ clsp,
                         const float* __restrict__ regp, float* __restrict__ outb)
{
  int i = blockIdx.x * 256 + threadIdx.x;
  if (i >= NB * NPOS) return;
  int p = i % NPOS;
  float gx = (float)(p % FMPX), gy = (float)(p / FMPX);
  float4 rg = *(const float4*)&regp[(size_t)i * 4];
  float cx = 1.f / (1.f + expf(-rg.x)) + gx;
  float cy = 1.f / (1.f + expf(-rg.y)) + gy;
  float whw = expf(rg.z), whh = expf(rg.w);
  float x1 = fminf(fmaxf((cx - whw * 0.5f) * BSCALE, 0.f), 1.f);
  float y1 = fminf(fmaxf((cy - whh * 0.5f) * BSCALE, 0.f), 1.f);
  float x2 = fminf(fmaxf((cx + whw * 0.5f) * BSCALE, 0.f), 1.f);
  float y2 = fminf(fmaxf((cy + whh * 0.5f) * BSCALE, 0.f), 1.f);
  outb[(size_t)i * 4 + 0] = x1; outb[(size_t)i * 4 + 1] = y1;
  outb[(size_t)i * 4 + 2] = x2; outb[(size_t)i * 4 + 3] = y2;

  float so = 1.f / (1.f + expf(-obj[i]));
  float cv[20];
  const float4* cp = (const float4*)&clsp[(size_t)i * 20];
#pragma unroll
  for (int q = 0; q < 5; q++) {
    float4 v4 = cp[q];
    cv[q * 4] = v4.x; cv[q * 4 + 1] = v4.y; cv[q * 4 + 2] = v4.z; cv[q * 4 + 3] = v4.w;
  }
  float mx = cv[0];
#pragma unroll
  for (int c = 1; c < 20; c++) mx = fmaxf(mx, cv[c]);
  float sum = 0.f;
#pragma unroll
  for (int c = 0; c < 20; c++) { cv[c] = expf(cv[c] - mx); sum += cv[c]; }
  float inv = so / sum;
  float best = -1.f; int bi = 0;
#pragma unroll
  for (int c = 0; c < 20; c++) { float s = cv[c] * inv; if (s > best) { best = s; bi = c; } }
  outb[SC_OFF + i] = best;
  outb[CLS_OFF + i] = (float)bi;
  outb[KEEP_OFF + i] = 0.f;
}

// ---------------- per (batch,class) greedy NMS ----------------------------
__device__ inline unsigned ordf(float f) {
  unsigned u = __float_as_uint(f);
  return (u & 0x80000000u) ? ~u : (u | 0x80000000u);
}

__global__ __launch_bounds__(64) void nms_k(const float* __restrict__ outb, float* __restrict__ keep_out)
{
  int b = blockIdx.x / NCLS, c = blockIdx.x % NCLS;
  int lane = threadIdx.x;
  __shared__ unsigned long long keys[512];
  __shared__ float bx1[384], by1[384], bx2[384], by2[384], bar[384];
  __shared__ unsigned kp[384];
  __shared__ int sj[384];

  for (int i = lane; i < 512; i += 64) {
    unsigned long long key = 0ULL;
    if (i < NPOS) {
      float sc = outb[SC_OFF + b * NPOS + i];
      int ci = (int)outb[CLS_OFF + b * NPOS + i];
      float s = (ci == c && sc >= CONF_T) ? sc : -1.0f;
      key = ((unsigned long long)ordf(s) << 32) | (unsigned)(~(unsigned)i);
    }
    keys[i] = key;
  }
  __syncthreads();
  for (int kk = 2; kk <= 512; kk <<= 1) {
    for (int jj = kk >> 1; jj > 0; jj >>= 1) {
      for (int i = lane; i < 512; i += 64) {
        int l2 = i ^ jj;
        if (l2 > i) {
          unsigned long long a = keys[i], bb2 = keys[l2];
          bool dir = (i & kk) == 0;
          bool sw = dir ? (a < bb2) : (a > bb2);
          if (sw) { keys[i] = bb2; keys[l2] = a; }
        }
      }
      __syncthreads();
    }
  }
  unsigned ordc = ordf(CONF_T);
  int nvalid = 0;
  for (int i = lane; i < 384; i += 64) {
    unsigned long long key = keys[i];
    unsigned hi = (unsigned)(key >> 32);
    int j = (int)(~(unsigned)key);
    bool valid = (key != 0ULL) && (hi >= ordc);
    kp[i] = valid ? 1u : 0u;
    if (valid) {
      const float* bp = &outb[(size_t)(b * NPOS + j) * 4];
      float x1 = bp[0], y1 = bp[1], x2 = bp[2], y2 = bp[3];
      bx1[i] = x1; by1[i] = y1; bx2[i] = x2; by2[i] = y2;
      bar[i] = (x2 - x1) * (y2 - y1);
      sj[i] = j;
    } else { bx1[i] = 0; by1[i] = 0; bx2[i] = 0; by2[i] = 0; bar[i] = 0; sj[i] = 0; }
    nvalid += __popcll(__ballot(valid));
  }
  __syncthreads();
  for (int i = 0; i < nvalid; ++i) {
    if (kp[i]) {
      float x1i = bx1[i], y1i = by1[i], x2i = bx2[i], y2i = by2[i], ai = bar[i];
      for (int j2 = i + 1 + lane; j2 < nvalid; j2 += 64) {
        if (kp[j2]) {
          float ww = fmaxf(1e-28f, fminf(x2i, bx2[j2]) - fmaxf(x1i, bx1[j2]));
          float hh = fmaxf(1e-28f, fminf(y2i, by2[j2]) - fmaxf(y1i, by1[j2]));
          float inter = ww * hh;
          float iou = inter / (ai + bar[j2] - inter + 1e-14f);
          if (iou > NMS_TH) kp[j2] = 0u;
        }
      }
    }
    __syncthreads();
  }
  for (int i = lane; i < 384; i += 64)
    if (kp[i]) keep_out[b * NPOS + sj[i]] = 1.0f;
}

extern "C" void kernel_launch(void* const* d_in, const int* in_sizes, int n_in,
                              void* d_out, int out_size, void* d_ws, size_t ws_size,
                              hipStream_t stream)
{
  const float* x      = (const float*)d_in[0];
  const float* w_cls1 = (const float*)d_in[1];  const float* b_cls1 = (const float*)d_in[2];
  const float* w_cls2 = (const float*)d_in[3];  const float* b_cls2 = (const float*)d_in[4];
  const float* w_reg1 = (const float*)d_in[5];  const float* b_reg1 = (const float*)d_in[6];
  const float* w_reg2 = (const float*)d_in[7];  const float* b_reg2 = (const float*)d_in[8];
  const float* w_reg3 = (const float*)d_in[9];  const float* b_reg3 = (const float*)d_in[10];
  const float* w_reg4 = (const float*)d_in[11]; const float* b_reg4 = (const float*)d_in[12];
  const float* w_obj  = (const float*)d_in[13]; const float* b_obj  = (const float*)d_in[14];
  const float* w_clsh = (const float*)d_in[15]; const float* b_clsh = (const float*)d_in[16];
  const float* w_regh = (const float*)d_in[17]; const float* b_regh = (const float*)d_in[18];
  float* outb = (float*)d_out;

  __bf16* XsA = (__bf16*)d_ws;
  __bf16* XsB = XsA + 2*PLANE;
  __bf16* Wg  = XsB + 2*PLANE;
  float* obj  = (float*)(Wg + (size_t)16*WSL);
  float* regp = obj + NB*NPOS;
  float* clsp = regp + (size_t)NB*NPOS*4;

  auto conv = [&](const float* wsrc, const float* bsrc, const __bf16* src, __bf16* dst) {
    repack_k<<<dim3(16, 32), 256, 0, stream>>>(wsrc, Wg);
    conv3x3_mfma<<<512, 256, 0, stream>>>(src, Wg, bsrc, dst);
  };

  split_x_k<<<dim3(64, NB), 256, 0, stream>>>(x, XsA);
  conv(w_reg1, b_reg1, XsA, XsB);
  conv(w_reg2, b_reg2, XsB, XsA);
  conv(w_reg3, b_reg3, XsA, XsB);
  conv(w_reg4, b_reg4, XsB, XsA);                    // rf = XsA
  head_rf_k<<<1444, 256, 0, stream>>>(XsA, w_obj, b_obj, w_regh, b_regh, obj, regp);
  split_x_k<<<dim3(64, NB), 256, 0, stream>>>(x, XsB);
  conv(w_cls1, b_cls1, XsB, XsA);
  conv(w_cls2, b_cls2, XsA, XsB);                    // cf = XsB
  head_cls_k<<<1444, 256, 0, stream>>>(XsB, w_clsh, b_clsh, clsp);
  decode_k<<<(NB * NPOS + 255) / 256, 256, 0, stream>>>(obj, clsp, regp, outb);
  nms_k<<<NB * NCLS, 64, 0, stream>>>(outb, outb + KEEP_OFF);
}

// Round 11
// 727.306 us; speedup vs baseline: 4.5705x; 1.1496x over previous
//
#include <hip/hip_runtime.h>
#include <hip/hip_bf16.h>
#include <stdint.h>

typedef __bf16 bf16x8 __attribute__((ext_vector_type(8)));
typedef float  f32x16 __attribute__((ext_vector_type(16)));

#define FMPX 19
#define NPOS 361
#define CCH  512
#define NB   16
#define NCLS 20
#define CONF_T 0.001f
#define NMS_TH 0.6f
#define BSCALE (32.0f/608.0f)

#define SC_OFF   (NB*NPOS*4)
#define CLS_OFF  (SC_OFF + NB*NPOS)
#define KEEP_OFF (CLS_OFF + NB*NPOS)

#define GSTR  3528                     // 441 rows * 8 ci elems
#define PLANE ((size_t)3612672)        // 16 b * 64 g * 3528 elems per split plane
#define WSL   294912                   // W elems per slice: 2pl*9t*32ch*512
#define XBUF  16384                    // 2pl * 2kh * 4096B
#define WBUF  18432                    // 2pl * 9tap * 2kh * 32co * 16B
#define WOFF  32768                    // 2*XBUF
#define SMEMB 69632                    // 2*XBUF + 2*WBUF (>= Lf 55296)

__device__ __forceinline__ void gl_lds16(const void* g, void* l) {
  __builtin_amdgcn_global_load_lds(
      (const __attribute__((address_space(1))) unsigned int*)g,
      (__attribute__((address_space(3))) unsigned int*)l, 16, 0, 0);
}
#define MFMA32(A,B,C) __builtin_amdgcn_mfma_f32_32x32x16_bf16(A,B,C,0,0,0)
#define SBAR() __builtin_amdgcn_sched_barrier(0)
#define PRIO1 __builtin_amdgcn_s_setprio(1)
#define PRIO0 __builtin_amdgcn_s_setprio(0)

// ---------------- split x: f32 NCHW -> 2 bf16 planes [pl][b][g][row441][8ci]
__global__ void split_x_k(const float* __restrict__ x, __bf16* __restrict__ Xd) {
  __shared__ float sx[8][368];
  int g = blockIdx.x, b = blockIdx.y;
  int tid = threadIdx.x;
  for (int i = tid; i < 8*361; i += 256) {
    int ci = i / 361, p = i - ci*361;
    sx[ci][p] = x[((size_t)b*CCH + g*8 + ci)*NPOS + p];
  }
  __syncthreads();
  for (int row = tid; row < 441; row += 256) {
    int y = row/21, xx = row - y*21;
    bf16x8 oh = {}, om = {};
    if (y >= 1 && y <= 19 && xx >= 1 && xx <= 19) {
      int p = (y-1)*19 + xx - 1;
#pragma unroll
      for (int j = 0; j < 8; ++j) {
        float v = sx[j][p];
        __bf16 hh = (__bf16)v;
        oh[j] = hh; om[j] = (__bf16)(v - (float)hh);
      }
    }
    size_t o = (((size_t)b)*64 + g)*GSTR + (size_t)row*8;
    *(bf16x8*)(Xd + o)         = oh;
    *(bf16x8*)(Xd + PLANE + o) = om;
  }
}

// ---------------- weight repack+split: w[co][ci][3][3] f32 ->
//  Wg [slice16][pl2][tap9][chunk32][kh2][co32][8ci] bf16
__global__ void repack_k(const float* __restrict__ w, __bf16* __restrict__ Wg) {
  __shared__ float sw[32][145];
  int slice = blockIdx.x, chunk = blockIdx.y;
  int tid = threadIdx.x;
  for (int i = tid; i < 32*144; i += 256) {
    int cl = i / 144, r = i - cl*144;
    sw[cl][r] = w[((size_t)slice*32 + cl)*4608 + chunk*144 + r];
  }
  __syncthreads();
  for (int u = tid; u < 1152; u += 256) {
    int co = u & 31, kh = (u >> 5) & 1, pt = u >> 6;   // pt 0..17
    int tap = pt % 9, pl = pt / 9;
    bf16x8 o;
#pragma unroll
    for (int j = 0; j < 8; ++j) {
      float v = sw[co][(kh*8 + j)*9 + tap];
      __bf16 hh = (__bf16)v;
      o[j] = pl == 0 ? hh : (__bf16)(v - (float)hh);
    }
    *(bf16x8*)(Wg + (((size_t)(slice*2 + pl)*9 + tap)*32 + chunk)*512 + kh*256 + co*8) = o;
  }
}

// read 6 m-tile A fragments at per-tap offsets (+IMM selects plane: 0=h, 8192=m)
#define RD6X(SP, AT, IMM) do { \
  SP##0 = *(const bf16x8*)(Xc + AT##0 + (IMM)); \
  SP##1 = *(const bf16x8*)(Xc + AT##1 + (IMM)); \
  SP##2 = *(const bf16x8*)(Xc + AT##2 + (IMM)); \
  SP##3 = *(const bf16x8*)(Xc + AT##3 + (IMM)); \
  SP##4 = *(const bf16x8*)(Xc + AT##4 + (IMM)); \
  SP##5 = *(const bf16x8*)(Xc + AT##5 + (IMM)); } while (0)

#define CL(SP, BH_, BM_) do { PRIO1; \
  acc0 = MFMA32(SP##0, BH_, acc0); acc1 = MFMA32(SP##1, BH_, acc1); \
  acc2 = MFMA32(SP##2, BH_, acc2); acc3 = MFMA32(SP##3, BH_, acc3); \
  acc4 = MFMA32(SP##4, BH_, acc4); acc5 = MFMA32(SP##5, BH_, acc5); \
  acc0 = MFMA32(SP##0, BM_, acc0); acc1 = MFMA32(SP##1, BM_, acc1); \
  acc2 = MFMA32(SP##2, BM_, acc2); acc3 = MFMA32(SP##3, BM_, acc3); \
  acc4 = MFMA32(SP##4, BM_, acc4); acc5 = MFMA32(SP##5, BM_, acc5); \
  PRIO0; } while (0)

#define CLH(SP, B_) do { PRIO1; \
  acc0 = MFMA32(SP##0, B_, acc0); acc1 = MFMA32(SP##1, B_, acc1); \
  acc2 = MFMA32(SP##2, B_, acc2); acc3 = MFMA32(SP##3, B_, acc3); \
  acc4 = MFMA32(SP##4, B_, acc4); acc5 = MFMA32(SP##5, B_, acc5); \
  PRIO0; } while (0)

#define STO(A, MTL) do { _Pragma("unroll") \
  for (int r = 0; r < 16; ++r) { \
    Lf[wq*3456 + ((MTL)*32 + 4*kh + (r & 3) + 8*(r >> 2))*36 + col] = (A)[r]; } } while (0)

// ---------------- 3x3 conv: bf16x2, 4 products {hh,hm,mh,mm}
// grid 512 (b,slice,h); block 256 = 4 waves, TAP-MAJOR roles:
// wave w owns taps {2w,2w+1} with ALL 4 products (reads Ah+Am once, 14 b128 ->
// 24 MFMA) plus tap-8 product #w (7 reads -> 6 MFMA). 35 reads / 54 MFMA per
// wave per chunk (was 45/54); 3 read-phases instead of 6.
__global__ __launch_bounds__(256, 2) void conv3x3_mfma(
    const __bf16* __restrict__ Xs, const __bf16* __restrict__ Wg,
    const float* __restrict__ bias, __bf16* __restrict__ Xd)
{
  __shared__ __attribute__((aligned(16))) char smem[SMEMB];
  const int tid = threadIdx.x;
  const int bid = blockIdx.x;
  const int b = bid & 15, slice = (bid >> 4) & 15, h = bid >> 8;
  const int lane = tid & 63;
  const int wq = __builtin_amdgcn_readfirstlane(tid >> 6);
  const int col = lane & 31, kh = lane >> 5;
  const int kh4096 = kh*4096;
  const int PB = h*190, CNT = h ? 171 : 190;
  const int PEND = PB + CNT - 1;
  const int clampU = h ? 230 : 251;

  // per-m-tile base LDS offsets (local padded row * 16)
  int ab0, ab1, ab2, ab3, ab4, ab5;
  {
    int ao[6];
#pragma unroll
    for (int mt = 0; mt < 6; ++mt) {
      int p = PB + mt*32 + col; if (p > PEND) p = PEND;
      int pp = p + 2*(p/19) + 22;
      ao[mt] = (pp - h*210)*16;
    }
    ab0 = ao[0]; ab1 = ao[1]; ab2 = ao[2]; ab3 = ao[3]; ab4 = ao[4]; ab5 = ao[5];
  }
  const int boff = kh*512 + col*16;

  // per-wave tap assignment
  const int goffs[9] = {-352,-336,-320,-16,0,16,320,336,352};
  const int t0 = 2*wq, t1 = t0 + 1;
  const int g0 = goffs[t0], g1 = goffs[t1];
  const int a8im = 352 + ((wq & 2) ? 8192 : 0);   // tap8 A plane by role
  const int t0a0 = ab0+g0, t0a1 = ab1+g0, t0a2 = ab2+g0,
            t0a3 = ab3+g0, t0a4 = ab4+g0, t0a5 = ab5+g0;
  const int t1a0 = ab0+g1, t1a1 = ab1+g1, t1a2 = ab2+g1,
            t1a3 = ab3+g1, t1a4 = ab4+g1, t1a5 = ab5+g1;
  const int t8a0 = ab0+a8im, t8a1 = ab1+a8im, t8a2 = ab2+a8im,
            t8a3 = ab3+a8im, t8a4 = ab4+a8im, t8a5 = ab5+a8im;
  const int wb0 = t0*1024 + boff, wb1 = t1*1024 + boff;
  const int wb8 = 8192 + boff + ((wq & 1) ? 9216 : 0);   // tap8 B plane by role

  // X staging: 4 insts/thread, slot r -> (pl,khs)=(r>>1,r&1), column block j=wq
  int ux = wq*64 + lane; if (ux > clampU) ux = clampU;
  const __bf16* xsb = Xs + (size_t)b*64*GSTR + (size_t)(h*210 + ux)*8;
  // W staging: 5 slots/wave, wk = wq*5+q (skip wk>=18); precomputed scalar offs
  const __bf16* wsb = Wg + (size_t)slice*WSL + (size_t)lane*8;
  int wsrc0, wsrc1, wsrc2, wsrc3, wsrc4;
  int wdst0, wdst1, wdst2, wdst3, wdst4;
  {
    int ws[5], wd[5];
#pragma unroll
    for (int q = 0; q < 5; ++q) {
      int wk = wq*5 + q; if (wk > 17) wk = 17;
      int pl = wk > 8 ? 1 : 0, tap = wk - 9*pl;
      ws[q] = ((pl*9 + tap)*32)*512;
      wd[q] = WOFF + pl*9216 + tap*1024;
    }
    wsrc0 = ws[0]; wsrc1 = ws[1]; wsrc2 = ws[2]; wsrc3 = ws[3]; wsrc4 = ws[4];
    wdst0 = wd[0]; wdst1 = wd[1]; wdst2 = wd[2]; wdst3 = wd[3]; wdst4 = wd[4];
  }
  const bool wv3 = (wq*5 + 3) < 18, wv4 = (wq*5 + 4) < 18;

  auto stage = [&](int c1, int buf) {
    const __bf16* xs = xsb + (size_t)(2*c1)*GSTR;
    char* xd = smem + (buf ? XBUF : 0) + wq*1024;
    gl_lds16(xs,                    xd);
    gl_lds16(xs + GSTR,             xd + 4096);
    gl_lds16(xs + PLANE,            xd + 8192);
    gl_lds16(xs + PLANE + GSTR,     xd + 12288);
    const __bf16* wsc = wsb + (size_t)c1*512;
    char* wb = smem + (buf ? WBUF : 0);
    gl_lds16(wsc + wsrc0, wb + wdst0);
    gl_lds16(wsc + wsrc1, wb + wdst1);
    gl_lds16(wsc + wsrc2, wb + wdst2);
    if (wv3) gl_lds16(wsc + wsrc3, wb + wdst3);
    if (wv4) gl_lds16(wsc + wsrc4, wb + wdst4);
  };

  f32x16 acc0 = {}, acc1 = {}, acc2 = {}, acc3 = {}, acc4 = {}, acc5 = {};

  stage(0, 0);
  __syncthreads();

  for (int c = 0; c < 32; ++c) {
    const char* Xc = smem + (c & 1)*XBUF + kh4096;
    const char* Wc = smem + WOFF + (c & 1)*WBUF;
    if (c < 31) stage(c + 1, (c + 1) & 1);

    bf16x8 H0, H1, H2, H3, H4, H5;
    bf16x8 M0, M1, M2, M3, M4, M5;
    bf16x8 N0, N1, N2, N3, N4, N5;
    bf16x8 B0h, B0m, B1h, B1m, B8;

    // phase 1: tap t0 operands (Ah first), then prefetch Am(t0)+Ah(t1)+B(t1)
    RD6X(H, t0a, 0);
    B0h = *(const bf16x8*)(Wc + wb0);
    B0m = *(const bf16x8*)(Wc + wb0 + 9216);
    SBAR();
    RD6X(M, t0a, 8192);
    RD6X(N, t1a, 0);
    B1h = *(const bf16x8*)(Wc + wb1);
    B1m = *(const bf16x8*)(Wc + wb1 + 9216);
    SBAR();
    CL(H, B0h, B0m);          // t0: hh, hm
    SBAR();
    CL(M, B0h, B0m);          // t0: mh, mm
    SBAR();
    // phase 2: prefetch Am(t1) + tap8 operands
    RD6X(M, t1a, 8192);
    RD6X(H, t8a, 0);
    B8 = *(const bf16x8*)(Wc + wb8);
    SBAR();
    CL(N, B1h, B1m);          // t1: hh, hm
    SBAR();
    CL(M, B1h, B1m);          // t1: mh, mm
    SBAR();
    CLH(H, B8);               // tap8: this wave's product
    __syncthreads();
  }

  // epilogue: 4 partials (one per wave) in Lf[4][96][36]; combine+bias+leaky+split
  float* Lf = (float*)smem;
#pragma unroll
  for (int half = 0; half < 2; ++half) {
    if (half == 0) { STO(acc0, 0); STO(acc1, 1); STO(acc2, 2); }
    else           { STO(acc3, 0); STO(acc4, 1); STO(acc5, 2); }
    __syncthreads();
    for (int u = tid; u < 768; u += 256) {
      int pl = u / 384, rem = u - pl*384;
      int gq = rem / 96, lp = rem - gq*96;
      int lpos = half*96 + lp;
      if (lpos < CNT) {
        int p = PB + lpos;
        int pp = p + 2*(p/19) + 22;
        const float* bb = bias + slice*32 + gq*8;
        bf16x8 o;
#pragma unroll
        for (int j = 0; j < 8; ++j) {
          int coix = lp*36 + gq*8 + j;
          float v = Lf[coix] + Lf[3456 + coix] + Lf[6912 + coix] + Lf[10368 + coix] + bb[j];
          v = v > 0.f ? v : 0.1f*v;
          __bf16 hh = (__bf16)v;
          o[j] = pl == 0 ? hh : (__bf16)(v - (float)hh);
        }
        *(bf16x8*)(Xd + (((size_t)pl*16 + b)*64 + slice*4 + gq)*GSTR + (size_t)pp*8) = o;
      }
    }
    __syncthreads();
  }

  // zero output halo rows for this h-half (halo columns are x=0 and x=20)
  const int nh = h ? 39 : 41;
  for (int u = tid; u < 8*nh; u += 256) {
    int pl = u / (4*nh); int rem = u - pl*4*nh;
    int gq = rem / nh; int ci2 = rem - gq*nh;
    int rowpos;
    if (ci2 < 21) rowpos = h ? (420 + ci2) : ci2;
    else { int q = ci2 - 21; rowpos = ((h ? 11 : 1) + (q >> 1))*21 + 20*(q & 1); }
    bf16x8 z = {};
    *(bf16x8*)(Xd + (((size_t)pl*16 + b)*64 + slice*4 + gq)*GSTR + (size_t)rowpos*8) = z;
  }
}

// ---------------- 1x1 heads on split planes ----------------
__global__ __launch_bounds__(256) void head_rf_k(
    const __bf16* __restrict__ F, const float* __restrict__ wobj,
    const float* __restrict__ bobj, const float* __restrict__ wreg,
    const float* __restrict__ breg, float* __restrict__ obj, float* __restrict__ regp)
{
  int gw = blockIdx.x*4 + (threadIdx.x >> 6);
  if (gw >= NB*NPOS) return;
  int lane = threadIdx.x & 63;
  int b = gw / NPOS, p = gw % NPOS;
  int pp = p + 2*(p/19) + 22;
  const __bf16* base = F + (((size_t)b)*64 + lane)*GSTR + (size_t)pp*8;
  bf16x8 v0 = *(const bf16x8*)base;
  bf16x8 v1 = *(const bf16x8*)(base + PLANE);
  float f[8];
#pragma unroll
  for (int j = 0; j < 8; ++j) f[j] = (float)v0[j] + (float)v1[j];
#pragma unroll
  for (int o = 0; o < 5; ++o) {
    const float* wp = (o == 0) ? wobj : wreg + (o-1)*CCH;
    float4 wa = *(const float4*)(wp + lane*8);
    float4 wb = *(const float4*)(wp + lane*8 + 4);
    float s2 = f[0]*wa.x + f[1]*wa.y + f[2]*wa.z + f[3]*wa.w
             + f[4]*wb.x + f[5]*wb.y + f[6]*wb.z + f[7]*wb.w;
#pragma unroll
    for (int d = 32; d; d >>= 1) s2 += __shfl_xor(s2, d);
    if (lane == 0) {
      if (o == 0) obj[gw] = s2 + bobj[0];
      else regp[(size_t)gw*4 + (o-1)] = s2 + breg[o-1];
    }
  }
}

__global__ __launch_bounds__(256) void head_cls_k(
    const __bf16* __restrict__ F, const float* __restrict__ wcls,
    const float* __restrict__ bcls, float* __restrict__ clsp)
{
  int gw = blockIdx.x*4 + (threadIdx.x >> 6);
  if (gw >= NB*NPOS) return;
  int lane = threadIdx.x & 63;
  int b = gw / NPOS, p = gw % NPOS;
  int pp = p + 2*(p/19) + 22;
  const __bf16* base = F + (((size_t)b)*64 + lane)*GSTR + (size_t)pp*8;
  bf16x8 v0 = *(const bf16x8*)base;
  bf16x8 v1 = *(const bf16x8*)(base + PLANE);
  float f[8];
#pragma unroll
  for (int j = 0; j < 8; ++j) f[j] = (float)v0[j] + (float)v1[j];
#pragma unroll
  for (int o = 0; o < NCLS; ++o) {
    const float* wp = wcls + o*CCH;
    float4 wa = *(const float4*)(wp + lane*8);
    float4 wb = *(const float4*)(wp + lane*8 + 4);
    float s2 = f[0]*wa.x + f[1]*wa.y + f[2]*wa.z + f[3]*wa.w
             + f[4]*wb.x + f[5]*wb.y + f[6]*wb.z + f[7]*wb.w;
#pragma unroll
    for (int d = 32; d; d >>= 1) s2 += __shfl_xor(s2, d);
    if (lane == 0) clsp[(size_t)gw*NCLS + o] = s2 + bcls[o];
  }
}

// ---------------- decode boxes + scores + argmax -------------------------
__global__ void decode_k(const float* __restrict__ obj, const float* __restrict__ clsp,
                         const float* __restrict__ regp, float* __restrict__ outb)
{
  int i = blockIdx.x * 256 + threadIdx.x;
  if (i >= NB * NPOS) return;
  int p = i % NPOS;
  float gx = (float)(p % FMPX), gy = (float)(p / FMPX);
  float4 rg = *(const float4*)&regp[(size_t)i * 4];
  float cx = 1.f / (1.f + expf(-rg.x)) + gx;
  float cy = 1.f / (1.f + expf(-rg.y)) + gy;
  float whw = expf(rg.z), whh = expf(rg.w);
  float x1 = fminf(fmaxf((cx - whw * 0.5f) * BSCALE, 0.f), 1.f);
  float y1 = fminf(fmaxf((cy - whh * 0.5f) * BSCALE, 0.f), 1.f);
  float x2 = fminf(fmaxf((cx + whw * 0.5f) * BSCALE, 0.f), 1.f);
  float y2 = fminf(fmaxf((cy + whh * 0.5f) * BSCALE, 0.f), 1.f);
  outb[(size_t)i * 4 + 0] = x1; outb[(size_t)i * 4 + 1] = y1;
  outb[(size_t)i * 4 + 2] = x2; outb[(size_t)i * 4 + 3] = y2;

  float so = 1.f / (1.f + expf(-obj[i]));
  float cv[20];
  const float4* cp = (const float4*)&clsp[(size_t)i * 20];
#pragma unroll
  for (int q = 0; q < 5; q++) {
    float4 v4 = cp[q];
    cv[q * 4] = v4.x; cv[q * 4 + 1] = v4.y; cv[q * 4 + 2] = v4.z; cv[q * 4 + 3] = v4.w;
  }
  float mx = cv[0];
#pragma unroll
  for (int c = 1; c < 20; c++) mx = fmaxf(mx, cv[c]);
  float sum = 0.f;
#pragma unroll
  for (int c = 0; c < 20; c++) { cv[c] = expf(cv[c] - mx); sum += cv[c]; }
  float inv = so / sum;
  float best = -1.f; int bi = 0;
#pragma unroll
  for (int c = 0; c < 20; c++) { float s = cv[c] * inv; if (s > best) { best = s; bi = c; } }
  outb[SC_OFF + i] = best;
  outb[CLS_OFF + i] = (float)bi;
  outb[KEEP_OFF + i] = 0.f;
}

// ---------------- per (batch,class) greedy NMS ----------------------------
__device__ inline unsigned ordf(float f) {
  unsigned u = __float_as_uint(f);
  return (u & 0x80000000u) ? ~u : (u | 0x80000000u);
}

__global__ __launch_bounds__(64) void nms_k(const float* __restrict__ outb, float* __restrict__ keep_out)
{
  int b = blockIdx.x / NCLS, c = blockIdx.x % NCLS;
  int lane = threadIdx.x;
  __shared__ unsigned long long keys[512];
  __shared__ float bx1[384], by1[384], bx2[384], by2[384], bar[384];
  __shared__ unsigned kp[384];
  __shared__ int sj[384];

  for (int i = lane; i < 512; i += 64) {
    unsigned long long key = 0ULL;
    if (i < NPOS) {
      float sc = outb[SC_OFF + b * NPOS + i];
      int ci = (int)outb[CLS_OFF + b * NPOS + i];
      float s = (ci == c && sc >= CONF_T) ? sc : -1.0f;
      key = ((unsigned long long)ordf(s) << 32) | (unsigned)(~(unsigned)i);
    }
    keys[i] = key;
  }
  __syncthreads();
  for (int kk = 2; kk <= 512; kk <<= 1) {
    for (int jj = kk >> 1; jj > 0; jj >>= 1) {
      for (int i = lane; i < 512; i += 64) {
        int l2 = i ^ jj;
        if (l2 > i) {
          unsigned long long a = keys[i], bb2 = keys[l2];
          bool dir = (i & kk) == 0;
          bool sw = dir ? (a < bb2) : (a > bb2);
          if (sw) { keys[i] = bb2; keys[l2] = a; }
        }
      }
      __syncthreads();
    }
  }
  unsigned ordc = ordf(CONF_T);
  int nvalid = 0;
  for (int i = lane; i < 384; i += 64) {
    unsigned long long key = keys[i];
    unsigned hi = (unsigned)(key >> 32);
    int j = (int)(~(unsigned)key);
    bool valid = (key != 0ULL) && (hi >= ordc);
    kp[i] = valid ? 1u : 0u;
    if (valid) {
      const float* bp = &outb[(size_t)(b * NPOS + j) * 4];
      float x1 = bp[0], y1 = bp[1], x2 = bp[2], y2 = bp[3];
      bx1[i] = x1; by1[i] = y1; bx2[i] = x2; by2[i] = y2;
      bar[i] = (x2 - x1) * (y2 - y1);
      sj[i] = j;
    } else { bx1[i] = 0; by1[i] = 0; bx2[i] = 0; by2[i] = 0; bar[i] = 0; sj[i] = 0; }
    nvalid += __popcll(__ballot(valid));
  }
  __syncthreads();
  for (int i = 0; i < nvalid; ++i) {
    if (kp[i]) {
      float x1i = bx1[i], y1i = by1[i], x2i = bx2[i], y2i = by2[i], ai = bar[i];
      for (int j2 = i + 1 + lane; j2 < nvalid; j2 += 64) {
        if (kp[j2]) {
          float ww = fmaxf(1e-28f, fminf(x2i, bx2[j2]) - fmaxf(x1i, bx1[j2]));
          float hh = fmaxf(1e-28f, fminf(y2i, by2[j2]) - fmaxf(y1i, by1[j2]));
          float inter = ww * hh;
          float iou = inter / (ai + bar[j2] - inter + 1e-14f);
          if (iou > NMS_TH) kp[j2] = 0u;
        }
      }
    }
    __syncthreads();
  }
  for (int i = lane; i < 384; i += 64)
    if (kp[i]) keep_out[b * NPOS + sj[i]] = 1.0f;
}

extern "C" void kernel_launch(void* const* d_in, const int* in_sizes, int n_in,
                              void* d_out, int out_size, void* d_ws, size_t ws_size,
                              hipStream_t stream)
{
  const float* x      = (const float*)d_in[0];
  const float* w_cls1 = (const float*)d_in[1];  const float* b_cls1 = (const float*)d_in[2];
  const float* w_cls2 = (const float*)d_in[3];  const float* b_cls2 = (const float*)d_in[4];
  const float* w_reg1 = (const float*)d_in[5];  const float* b_reg1 = (const float*)d_in[6];
  const float* w_reg2 = (const float*)d_in[7];  const float* b_reg2 = (const float*)d_in[8];
  const float* w_reg3 = (const float*)d_in[9];  const float* b_reg3 = (const float*)d_in[10];
  const float* w_reg4 = (const float*)d_in[11]; const float* b_reg4 = (const float*)d_in[12];
  const float* w_obj  = (const float*)d_in[13]; const float* b_obj  = (const float*)d_in[14];
  const float* w_clsh = (const float*)d_in[15]; const float* b_clsh = (const float*)d_in[16];
  const float* w_regh = (const float*)d_in[17]; const float* b_regh = (const float*)d_in[18];
  float* outb = (float*)d_out;

  __bf16* XsA = (__bf16*)d_ws;
  __bf16* XsB = XsA + 2*PLANE;
  __bf16* Wg  = XsB + 2*PLANE;
  float* obj  = (float*)(Wg + (size_t)16*WSL);
  float* regp = obj + NB*NPOS;
  float* clsp = regp + (size_t)NB*NPOS*4;

  auto conv = [&](const float* wsrc, const float* bsrc, const __bf16* src, __bf16* dst) {
    repack_k<<<dim3(16, 32), 256, 0, stream>>>(wsrc, Wg);
    conv3x3_mfma<<<512, 256, 0, stream>>>(src, Wg, bsrc, dst);
  };

  split_x_k<<<dim3(64, NB), 256, 0, stream>>>(x, XsA);
  conv(w_reg1, b_reg1, XsA, XsB);
  conv(w_reg2, b_reg2, XsB, XsA);
  conv(w_reg3, b_reg3, XsA, XsB);
  conv(w_reg4, b_reg4, XsB, XsA);                    // rf = XsA
  head_rf_k<<<1444, 256, 0, stream>>>(XsA, w_obj, b_obj, w_regh, b_regh, obj, regp);
  split_x_k<<<dim3(64, NB), 256, 0, stream>>>(x, XsB);
  conv(w_cls1, b_cls1, XsB, XsA);
  conv(w_cls2, b_cls2, XsA, XsB);                    // cf = XsB
  head_cls_k<<<1444, 256, 0, stream>>>(XsB, w_clsh, b_clsh, clsp);
  decode_k<<<(NB * NPOS + 255) / 256, 256, 0, stream>>>(obj, clsp, regp, outb);
  nms_k<<<NB * NCLS, 64, 0, stream>>>(outb, outb + KEEP_OFF);
}

// Round 12
// 680.427 us; speedup vs baseline: 4.8854x; 1.0689x over previous
//
#include <hip/hip_runtime.h>
#include <hip/hip_bf16.h>
#include <stdint.h>

typedef __bf16 bf16x8 __attribute__((ext_vector_type(8)));
typedef float  f32x16 __attribute__((ext_vector_type(16)));

#define FMPX 19
#define NPOS 361
#define CCH  512
#define NB   16
#define NCLS 20
#define CONF_T 0.001f
#define NMS_TH 0.6f
#define BSCALE (32.0f/608.0f)

#define SC_OFF   (NB*NPOS*4)
#define CLS_OFF  (SC_OFF + NB*NPOS)
#define KEEP_OFF (CLS_OFF + NB*NPOS)

#define GSTR  3528                     // 441 rows * 8 ci elems
#define PLANE ((size_t)3612672)        // 16 b * 64 g * 3528 elems per split plane
#define WSL   294912                   // W elems per slice: 2pl*9t*32ch*512
#define XBUF  16384                    // 2pl * 2kh * 4096B
#define WBUF  18432                    // 2pl * 9tap * 2kh * 32co * 16B
#define WOFF  32768                    // 2*XBUF
#define SMEMB 69632                    // 2*XBUF + 2*WBUF (>= Lf 55296)

__device__ __forceinline__ void gl_lds16(const void* g, void* l) {
  __builtin_amdgcn_global_load_lds(
      (const __attribute__((address_space(1))) unsigned int*)g,
      (__attribute__((address_space(3))) unsigned int*)l, 16, 0, 0);
}
#define MFMA32(A,B,C) __builtin_amdgcn_mfma_f32_32x32x16_bf16(A,B,C,0,0,0)
#define SG(m,n) __builtin_amdgcn_sched_group_barrier(m, n, 0)
#define PRIO1 __builtin_amdgcn_s_setprio(1)
#define PRIO0 __builtin_amdgcn_s_setprio(0)

// ---------------- split x: f32 NCHW -> 2 bf16 planes [pl][b][g][row441][8ci]
__global__ void split_x_k(const float* __restrict__ x, __bf16* __restrict__ Xd) {
  __shared__ float sx[8][368];
  int g = blockIdx.x, b = blockIdx.y;
  int tid = threadIdx.x;
  for (int i = tid; i < 8*361; i += 256) {
    int ci = i / 361, p = i - ci*361;
    sx[ci][p] = x[((size_t)b*CCH + g*8 + ci)*NPOS + p];
  }
  __syncthreads();
  for (int row = tid; row < 441; row += 256) {
    int y = row/21, xx = row - y*21;
    bf16x8 oh = {}, om = {};
    if (y >= 1 && y <= 19 && xx >= 1 && xx <= 19) {
      int p = (y-1)*19 + xx - 1;
#pragma unroll
      for (int j = 0; j < 8; ++j) {
        float v = sx[j][p];
        __bf16 hh = (__bf16)v;
        oh[j] = hh; om[j] = (__bf16)(v - (float)hh);
      }
    }
    size_t o = (((size_t)b)*64 + g)*GSTR + (size_t)row*8;
    *(bf16x8*)(Xd + o)         = oh;
    *(bf16x8*)(Xd + PLANE + o) = om;
  }
}

// ---------------- weight repack+split: w[co][ci][3][3] f32 ->
//  Wg [slice16][pl2][tap9][chunk32][kh2][co32][8ci] bf16
__global__ void repack_k(const float* __restrict__ w, __bf16* __restrict__ Wg) {
  __shared__ float sw[32][145];
  int slice = blockIdx.x, chunk = blockIdx.y;
  int tid = threadIdx.x;
  for (int i = tid; i < 32*144; i += 256) {
    int cl = i / 144, r = i - cl*144;
    sw[cl][r] = w[((size_t)slice*32 + cl)*4608 + chunk*144 + r];
  }
  __syncthreads();
  for (int u = tid; u < 1152; u += 256) {
    int co = u & 31, kh = (u >> 5) & 1, pt = u >> 6;   // pt 0..17
    int tap = pt % 9, pl = pt / 9;
    bf16x8 o;
#pragma unroll
    for (int j = 0; j < 8; ++j) {
      float v = sw[co][(kh*8 + j)*9 + tap];
      __bf16 hh = (__bf16)v;
      o[j] = pl == 0 ? hh : (__bf16)(v - (float)hh);
    }
    *(bf16x8*)(Wg + (((size_t)(slice*2 + pl)*9 + tap)*32 + chunk)*512 + kh*256 + co*8) = o;
  }
}

// read 6 m-tile A fragments at per-tap offsets (+IMM selects plane: 0=h, 8192=m)
#define RD6X(SP, AT, IMM) do { \
  SP##0 = *(const bf16x8*)(Xc + AT##0 + (IMM)); \
  SP##1 = *(const bf16x8*)(Xc + AT##1 + (IMM)); \
  SP##2 = *(const bf16x8*)(Xc + AT##2 + (IMM)); \
  SP##3 = *(const bf16x8*)(Xc + AT##3 + (IMM)); \
  SP##4 = *(const bf16x8*)(Xc + AT##4 + (IMM)); \
  SP##5 = *(const bf16x8*)(Xc + AT##5 + (IMM)); } while (0)

#define CL(SP, BH_, BM_) do { \
  acc0 = MFMA32(SP##0, BH_, acc0); acc1 = MFMA32(SP##1, BH_, acc1); \
  acc2 = MFMA32(SP##2, BH_, acc2); acc3 = MFMA32(SP##3, BH_, acc3); \
  acc4 = MFMA32(SP##4, BH_, acc4); acc5 = MFMA32(SP##5, BH_, acc5); \
  acc0 = MFMA32(SP##0, BM_, acc0); acc1 = MFMA32(SP##1, BM_, acc1); \
  acc2 = MFMA32(SP##2, BM_, acc2); acc3 = MFMA32(SP##3, BM_, acc3); \
  acc4 = MFMA32(SP##4, BM_, acc4); acc5 = MFMA32(SP##5, BM_, acc5); } while (0)

#define CLH(SP, B_) do { \
  acc0 = MFMA32(SP##0, B_, acc0); acc1 = MFMA32(SP##1, B_, acc1); \
  acc2 = MFMA32(SP##2, B_, acc2); acc3 = MFMA32(SP##3, B_, acc3); \
  acc4 = MFMA32(SP##4, B_, acc4); acc5 = MFMA32(SP##5, B_, acc5); } while (0)

#define STO(A, MTL) do { _Pragma("unroll") \
  for (int r = 0; r < 16; ++r) { \
    Lf[wq*3456 + ((MTL)*32 + 4*kh + (r & 3) + 8*(r >> 2))*36 + col] = (A)[r]; } } while (0)

// ---------------- 3x3 conv: bf16x2, 4 products {hh,hm,mh,mm}
// grid 512 (b,slice,h); block 256 = 4 waves, tap-major roles (R11) plus:
// SBAR-free chunk body with a sched_group_barrier script that interleaves
// each cluster's 12 MFMA with the NEXT cluster's 6-8 ds_reads, so the LDS
// port runs under the matrix pipe instead of serializing with it.
__global__ __launch_bounds__(256, 2) void conv3x3_mfma(
    const __bf16* __restrict__ Xs, const __bf16* __restrict__ Wg,
    const float* __restrict__ bias, __bf16* __restrict__ Xd)
{
  __shared__ __attribute__((aligned(16))) char smem[SMEMB];
  const int tid = threadIdx.x;
  const int bid = blockIdx.x;
  const int b = bid & 15, slice = (bid >> 4) & 15, h = bid >> 8;
  const int lane = tid & 63;
  const int wq = __builtin_amdgcn_readfirstlane(tid >> 6);
  const int col = lane & 31, kh = lane >> 5;
  const int kh4096 = kh*4096;
  const int PB = h*190, CNT = h ? 171 : 190;
  const int PEND = PB + CNT - 1;
  const int clampU = h ? 230 : 251;

  // per-m-tile base LDS offsets (local padded row * 16)
  int ab0, ab1, ab2, ab3, ab4, ab5;
  {
    int ao[6];
#pragma unroll
    for (int mt = 0; mt < 6; ++mt) {
      int p = PB + mt*32 + col; if (p > PEND) p = PEND;
      int pp = p + 2*(p/19) + 22;
      ao[mt] = (pp - h*210)*16;
    }
    ab0 = ao[0]; ab1 = ao[1]; ab2 = ao[2]; ab3 = ao[3]; ab4 = ao[4]; ab5 = ao[5];
  }
  const int boff = kh*512 + col*16;

  // per-wave tap assignment
  const int goffs[9] = {-352,-336,-320,-16,0,16,320,336,352};
  const int t0 = 2*wq, t1 = t0 + 1;
  const int g0 = goffs[t0], g1 = goffs[t1];
  const int a8im = 352 + ((wq & 2) ? 8192 : 0);   // tap8 A plane by role
  const int t0a0 = ab0+g0, t0a1 = ab1+g0, t0a2 = ab2+g0,
            t0a3 = ab3+g0, t0a4 = ab4+g0, t0a5 = ab5+g0;
  const int t1a0 = ab0+g1, t1a1 = ab1+g1, t1a2 = ab2+g1,
            t1a3 = ab3+g1, t1a4 = ab4+g1, t1a5 = ab5+g1;
  const int t8a0 = ab0+a8im, t8a1 = ab1+a8im, t8a2 = ab2+a8im,
            t8a3 = ab3+a8im, t8a4 = ab4+a8im, t8a5 = ab5+a8im;
  const int wb0 = t0*1024 + boff, wb1 = t1*1024 + boff;
  const int wb8 = 8192 + boff + ((wq & 1) ? 9216 : 0);   // tap8 B plane by role

  // X staging: 4 insts/thread, slot r -> (pl,khs)=(r>>1,r&1), column block j=wq
  int ux = wq*64 + lane; if (ux > clampU) ux = clampU;
  const __bf16* xsb = Xs + (size_t)b*64*GSTR + (size_t)(h*210 + ux)*8;
  // W staging: 5 uniform slots/wave, wk = (wq*5+q) % 18 (wave3 dups slots 0,1
  // -- identical src/dst writes, benign; keeps stage() branch-free so the
  // chunk body stays ONE scheduling region for the SGB script)
  const __bf16* wsb = Wg + (size_t)slice*WSL + (size_t)lane*8;
  int wsrc0, wsrc1, wsrc2, wsrc3, wsrc4;
  int wdst0, wdst1, wdst2, wdst3, wdst4;
  {
    int ws[5], wd[5];
#pragma unroll
    for (int q = 0; q < 5; ++q) {
      int wk = (wq*5 + q) % 18;
      int pl = wk > 8 ? 1 : 0, tap = wk - 9*pl;
      ws[q] = ((pl*9 + tap)*32)*512;
      wd[q] = WOFF + pl*9216 + tap*1024;
    }
    wsrc0 = ws[0]; wsrc1 = ws[1]; wsrc2 = ws[2]; wsrc3 = ws[3]; wsrc4 = ws[4];
    wdst0 = wd[0]; wdst1 = wd[1]; wdst2 = wd[2]; wdst3 = wd[3]; wdst4 = wd[4];
  }

  auto stage = [&](int c1, int buf) {
    const __bf16* xs = xsb + (size_t)(2*c1)*GSTR;
    char* xd = smem + (buf ? XBUF : 0) + wq*1024;
    gl_lds16(xs,                    xd);
    gl_lds16(xs + GSTR,             xd + 4096);
    gl_lds16(xs + PLANE,            xd + 8192);
    gl_lds16(xs + PLANE + GSTR,     xd + 12288);
    const __bf16* wsc = wsb + (size_t)c1*512;
    char* wb = smem + (buf ? WBUF : 0);
    gl_lds16(wsc + wsrc0, wb + wdst0);
    gl_lds16(wsc + wsrc1, wb + wdst1);
    gl_lds16(wsc + wsrc2, wb + wdst2);
    gl_lds16(wsc + wsrc3, wb + wdst3);
    gl_lds16(wsc + wsrc4, wb + wdst4);
  };

  f32x16 acc0 = {}, acc1 = {}, acc2 = {}, acc3 = {}, acc4 = {}, acc5 = {};

  stage(0, 0);
  __syncthreads();

  for (int c = 0; c < 32; ++c) {
    const char* Xc = smem + (c & 1)*XBUF + kh4096;
    const char* Wc = smem + WOFF + (c & 1)*WBUF;
    const int cn = (c < 31) ? (c + 1) : 31;    // branchless dup of last chunk

    bf16x8 A00, A01, A02, A03, A04, A05;
    bf16x8 A10, A11, A12, A13, A14, A15;
    bf16x8 B0h, B0m, B1h, B1m, B8v;

    // G0: Ah(t0) + B(t0)   [8 ds_read]
    RD6X(A0, t0a, 0);
    B0h = *(const bf16x8*)(Wc + wb0);
    B0m = *(const bf16x8*)(Wc + wb0 + 9216);
    // stage c+1   [9 vmem]
    stage(cn, (c + 1) & 1);
    PRIO1;
    // C0: t0 hh,hm  ||  read Am(t0) -> A1   [6 ds]
    RD6X(A1, t0a, 8192);
    CL(A0, B0h, B0m);
    // C1: t0 mh,mm  ||  read Ah(t1)+B(t1) -> A0,B1   [8 ds]
    RD6X(A0, t1a, 0);
    B1h = *(const bf16x8*)(Wc + wb1);
    B1m = *(const bf16x8*)(Wc + wb1 + 9216);
    CL(A1, B0h, B0m);
    // C2: t1 hh,hm  ||  read Am(t1) -> A1   [6 ds]
    RD6X(A1, t1a, 8192);
    CL(A0, B1h, B1m);
    // C3: t1 mh,mm  ||  read A(t8)+B(t8) -> A0,B8   [7 ds]
    RD6X(A0, t8a, 0);
    B8v = *(const bf16x8*)(Wc + wb8);
    CL(A1, B1h, B1m);
    // C4: tap8 product
    CLH(A0, B8v);
    PRIO0;

    // ---- schedule script: G0 reads, staging, then per-cluster interleave
    SG(0x100, 8);                 // G0: 8 ds_read
    SG(0x70, 9);                  // 9 global_load_lds
#pragma unroll
    for (int i = 0; i < 6; ++i) { SG(8, 2); SG(0x100, 1); }   // C0 || 6 ds
#pragma unroll
    for (int i = 0; i < 4; ++i) { SG(8, 3); SG(0x100, 2); }   // C1 || 8 ds
#pragma unroll
    for (int i = 0; i < 6; ++i) { SG(8, 2); SG(0x100, 1); }   // C2 || 6 ds
#pragma unroll
    for (int i = 0; i < 7; ++i) { SG(8, 1); SG(0x100, 1); }   // C3 || 7 ds
    SG(8, 11);                    // C3 tail + C4
    __syncthreads();
  }

  // epilogue: 4 partials (one per wave) in Lf[4][96][36]; combine+bias+leaky+split
  float* Lf = (float*)smem;
#pragma unroll
  for (int half = 0; half < 2; ++half) {
    if (half == 0) { STO(acc0, 0); STO(acc1, 1); STO(acc2, 2); }
    else           { STO(acc3, 0); STO(acc4, 1); STO(acc5, 2); }
    __syncthreads();
    for (int u = tid; u < 768; u += 256) {
      int pl = u / 384, rem = u - pl*384;
      int gq = rem / 96, lp = rem - gq*96;
      int lpos = half*96 + lp;
      if (lpos < CNT) {
        int p = PB + lpos;
        int pp = p + 2*(p/19) + 22;
        const float* bb = bias + slice*32 + gq*8;
        bf16x8 o;
#pragma unroll
        for (int j = 0; j < 8; ++j) {
          int coix = lp*36 + gq*8 + j;
          float v = Lf[coix] + Lf[3456 + coix] + Lf[6912 + coix] + Lf[10368 + coix] + bb[j];
          v = v > 0.f ? v : 0.1f*v;
          __bf16 hh = (__bf16)v;
          o[j] = pl == 0 ? hh : (__bf16)(v - (float)hh);
        }
        *(bf16x8*)(Xd + (((size_t)pl*16 + b)*64 + slice*4 + gq)*GSTR + (size_t)pp*8) = o;
      }
    }
    __syncthreads();
  }

  // zero output halo rows for this h-half (halo columns are x=0 and x=20)
  const int nh = h ? 39 : 41;
  for (int u = tid; u < 8*nh; u += 256) {
    int pl = u / (4*nh); int rem = u - pl*4*nh;
    int gq = rem / nh; int ci2 = rem - gq*nh;
    int rowpos;
    if (ci2 < 21) rowpos = h ? (420 + ci2) : ci2;
    else { int q = ci2 - 21; rowpos = ((h ? 11 : 1) + (q >> 1))*21 + 20*(q & 1); }
    bf16x8 z = {};
    *(bf16x8*)(Xd + (((size_t)pl*16 + b)*64 + slice*4 + gq)*GSTR + (size_t)rowpos*8) = z;
  }
}

// ---------------- 1x1 heads on split planes ----------------
__global__ __launch_bounds__(256) void head_rf_k(
    const __bf16* __restrict__ F, const float* __restrict__ wobj,
    const float* __restrict__ bobj, const float* __restrict__ wreg,
    const float* __restrict__ breg, float* __restrict__ obj, float* __restrict__ regp)
{
  int gw = blockIdx.x*4 + (threadIdx.x >> 6);
  if (gw >= NB*NPOS) return;
  int lane = threadIdx.x & 63;
  int b = gw / NPOS, p = gw % NPOS;
  int pp = p + 2*(p/19) + 22;
  const __bf16* base = F + (((size_t)b)*64 + lane)*GSTR + (size_t)pp*8;
  bf16x8 v0 = *(const bf16x8*)base;
  bf16x8 v1 = *(const bf16x8*)(base + PLANE);
  float f[8];
#pragma unroll
  for (int j = 0; j < 8; ++j) f[j] = (float)v0[j] + (float)v1[j];
#pragma unroll
  for (int o = 0; o < 5; ++o) {
    const float* wp = (o == 0) ? wobj : wreg + (o-1)*CCH;
    float4 wa = *(const float4*)(wp + lane*8);
    float4 wb = *(const float4*)(wp + lane*8 + 4);
    float s2 = f[0]*wa.x + f[1]*wa.y + f[2]*wa.z + f[3]*wa.w
             + f[4]*wb.x + f[5]*wb.y + f[6]*wb.z + f[7]*wb.w;
#pragma unroll
    for (int d = 32; d; d >>= 1) s2 += __shfl_xor(s2, d);
    if (lane == 0) {
      if (o == 0) obj[gw] = s2 + bobj[0];
      else regp[(size_t)gw*4 + (o-1)] = s2 + breg[o-1];
    }
  }
}

__global__ __launch_bounds__(256) void head_cls_k(
    const __bf16* __restrict__ F, const float* __restrict__ wcls,
    const float* __restrict__ bcls, float* __restrict__ clsp)
{
  int gw = blockIdx.x*4 + (threadIdx.x >> 6);
  if (gw >= NB*NPOS) return;
  int lane = threadIdx.x & 63;
  int b = gw / NPOS, p = gw % NPOS;
  int pp = p + 2*(p/19) + 22;
  const __bf16* base = F + (((size_t)b)*64 + lane)*GSTR + (size_t)pp*8;
  bf16x8 v0 = *(const bf16x8*)base;
  bf16x8 v1 = *(const bf16x8*)(base + PLANE);
  float f[8];
#pragma unroll
  for (int j = 0; j < 8; ++j) f[j] = (float)v0[j] + (float)v1[j];
#pragma unroll
  for (int o = 0; o < NCLS; ++o) {
    const float* wp = wcls + o*CCH;
    float4 wa = *(const float4*)(wp + lane*8);
    float4 wb = *(const float4*)(wp + lane*8 + 4);
    float s2 = f[0]*wa.x + f[1]*wa.y + f[2]*wa.z + f[3]*wa.w
             + f[4]*wb.x + f[5]*wb.y + f[6]*wb.z + f[7]*wb.w;
#pragma unroll
    for (int d = 32; d; d >>= 1) s2 += __shfl_xor(s2, d);
    if (lane == 0) clsp[(size_t)gw*NCLS + o] = s2 + bcls[o];
  }
}

// ---------------- decode boxes + scores + argmax -------------------------
__global__ void decode_k(const float* __restrict__ obj, const float* __restrict__ clsp,
                         const float* __restrict__ regp, float* __restrict__ outb)
{
  int i = blockIdx.x * 256 + threadIdx.x;
  if (i >= NB * NPOS) return;
  int p = i % NPOS;
  float gx = (float)(p % FMPX), gy = (float)(p / FMPX);
  float4 rg = *(const float4*)&regp[(size_t)i * 4];
  float cx = 1.f / (1.f + expf(-rg.x)) + gx;
  float cy = 1.f / (1.f + expf(-rg.y)) + gy;
  float whw = expf(rg.z), whh = expf(rg.w);
  float x1 = fminf(fmaxf((cx - whw * 0.5f) * BSCALE, 0.f), 1.f);
  float y1 = fminf(fmaxf((cy - whh * 0.5f) * BSCALE, 0.f), 1.f);
  float x2 = fminf(fmaxf((cx + whw * 0.5f) * BSCALE, 0.f), 1.f);
  float y2 = fminf(fmaxf((cy + whh * 0.5f) * BSCALE, 0.f), 1.f);
  outb[(size_t)i * 4 + 0] = x1; outb[(size_t)i * 4 + 1] = y1;
  outb[(size_t)i * 4 + 2] = x2; outb[(size_t)i * 4 + 3] = y2;

  float so = 1.f / (1.f + expf(-obj[i]));
  float cv[20];
  const float4* cp = (const float4*)&clsp[(size_t)i * 20];
#pragma unroll
  for (int q = 0; q < 5; q++) {
    float4 v4 = cp[q];
    cv[q * 4] = v4.x; cv[q * 4 + 1] = v4.y; cv[q * 4 + 2] = v4.z; cv[q * 4 + 3] = v4.w;
  }
  float mx = cv[0];
#pragma unroll
  for (int c = 1; c < 20; c++) mx = fmaxf(mx, cv[c]);
  float sum = 0.f;
#pragma unroll
  for (int c = 0; c < 20; c++) { cv[c] = expf(cv[c] - mx); sum += cv[c]; }
  float inv = so / sum;
  float best = -1.f; int bi = 0;
#pragma unroll
  for (int c = 0; c < 20; c++) { float s = cv[c] * inv; if (s > best) { best = s; bi = c; } }
  outb[SC_OFF + i] = best;
  outb[CLS_OFF + i] = (float)bi;
  outb[KEEP_OFF + i] = 0.f;
}

// ---------------- per (batch,class) greedy NMS ----------------------------
__device__ inline unsigned ordf(float f) {
  unsigned u = __float_as_uint(f);
  return (u & 0x80000000u) ? ~u : (u | 0x80000000u);
}

__global__ __launch_bounds__(64) void nms_k(const float* __restrict__ outb, float* __restrict__ keep_out)
{
  int b = blockIdx.x / NCLS, c = blockIdx.x % NCLS;
  int lane = threadIdx.x;
  __shared__ unsigned long long keys[512];
  __shared__ float bx1[384], by1[384], bx2[384], by2[384], bar[384];
  __shared__ unsigned kp[384];
  __shared__ int sj[384];

  for (int i = lane; i < 512; i += 64) {
    unsigned long long key = 0ULL;
    if (i < NPOS) {
      float sc = outb[SC_OFF + b * NPOS + i];
      int ci = (int)outb[CLS_OFF + b * NPOS + i];
      float s = (ci == c && sc >= CONF_T) ? sc : -1.0f;
      key = ((unsigned long long)ordf(s) << 32) | (unsigned)(~(unsigned)i);
    }
    keys[i] = key;
  }
  __syncthreads();
  for (int kk = 2; kk <= 512; kk <<= 1) {
    for (int jj = kk >> 1; jj > 0; jj >>= 1) {
      for (int i = lane; i < 512; i += 64) {
        int l2 = i ^ jj;
        if (l2 > i) {
          unsigned long long a = keys[i], bb2 = keys[l2];
          bool dir = (i & kk) == 0;
          bool sw = dir ? (a < bb2) : (a > bb2);
          if (sw) { keys[i] = bb2; keys[l2] = a; }
        }
      }
      __syncthreads();
    }
  }
  unsigned ordc = ordf(CONF_T);
  int nvalid = 0;
  for (int i = lane; i < 384; i += 64) {
    unsigned long long key = keys[i];
    unsigned hi = (unsigned)(key >> 32);
    int j = (int)(~(unsigned)key);
    bool valid = (key != 0ULL) && (hi >= ordc);
    kp[i] = valid ? 1u : 0u;
    if (valid) {
      const float* bp = &outb[(size_t)(b * NPOS + j) * 4];
      float x1 = bp[0], y1 = bp[1], x2 = bp[2], y2 = bp[3];
      bx1[i] = x1; by1[i] = y1; bx2[i] = x2; by2[i] = y2;
      bar[i] = (x2 - x1) * (y2 - y1);
      sj[i] = j;
    } else { bx1[i] = 0; by1[i] = 0; bx2[i] = 0; by2[i] = 0; bar[i] = 0; sj[i] = 0; }
    nvalid += __popcll(__ballot(valid));
  }
  __syncthreads();
  for (int i = 0; i < nvalid; ++i) {
    if (kp[i]) {
      float x1i = bx1[i], y1i = by1[i], x2i = bx2[i], y2i = by2[i], ai = bar[i];
      for (int j2 = i + 1 + lane; j2 < nvalid; j2 += 64) {
        if (kp[j2]) {
          float ww = fmaxf(1e-28f, fminf(x2i, bx2[j2]) - fmaxf(x1i, bx1[j2]));
          float hh = fmaxf(1e-28f, fminf(y2i, by2[j2]) - fmaxf(y1i, by1[j2]));
          float inter = ww * hh;
          float iou = inter / (ai + bar[j2] - inter + 1e-14f);
          if (iou > NMS_TH) kp[j2] = 0u;
        }
      }
    }
    __syncthreads();
  }
  for (int i = lane; i < 384; i += 64)
    if (kp[i]) keep_out[b * NPOS + sj[i]] = 1.0f;
}

extern "C" void kernel_launch(void* const* d_in, const int* in_sizes, int n_in,
                              void* d_out, int out_size, void* d_ws, size_t ws_size,
                              hipStream_t stream)
{
  const float* x      = (const float*)d_in[0];
  const float* w_cls1 = (const float*)d_in[1];  const float* b_cls1 = (const float*)d_in[2];
  const float* w_cls2 = (const float*)d_in[3];  const float* b_cls2 = (const float*)d_in[4];
  const float* w_reg1 = (const float*)d_in[5];  const float* b_reg1 = (const float*)d_in[6];
  const float* w_reg2 = (const float*)d_in[7];  const float* b_reg2 = (const float*)d_in[8];
  const float* w_reg3 = (const float*)d_in[9];  const float* b_reg3 = (const float*)d_in[10];
  const float* w_reg4 = (const float*)d_in[11]; const float* b_reg4 = (const float*)d_in[12];
  const float* w_obj  = (const float*)d_in[13]; const float* b_obj  = (const float*)d_in[14];
  const float* w_clsh = (const float*)d_in[15]; const float* b_clsh = (const float*)d_in[16];
  const float* w_regh = (const float*)d_in[17]; const float* b_regh = (const float*)d_in[18];
  float* outb = (float*)d_out;

  __bf16* XsA = (__bf16*)d_ws;
  __bf16* XsB = XsA + 2*PLANE;
  __bf16* Wg  = XsB + 2*PLANE;
  float* obj  = (float*)(Wg + (size_t)16*WSL);
  float* regp = obj + NB*NPOS;
  float* clsp = regp + (size_t)NB*NPOS*4;

  auto conv = [&](const float* wsrc, const float* bsrc, const __bf16* src, __bf16* dst) {
    repack_k<<<dim3(16, 32), 256, 0, stream>>>(wsrc, Wg);
    conv3x3_mfma<<<512, 256, 0, stream>>>(src, Wg, bsrc, dst);
  };

  split_x_k<<<dim3(64, NB), 256, 0, stream>>>(x, XsA);
  conv(w_reg1, b_reg1, XsA, XsB);
  conv(w_reg2, b_reg2, XsB, XsA);
  conv(w_reg3, b_reg3, XsA, XsB);
  conv(w_reg4, b_reg4, XsB, XsA);                    // rf = XsA
  head_rf_k<<<1444, 256, 0, stream>>>(XsA, w_obj, b_obj, w_regh, b_regh, obj, regp);
  split_x_k<<<dim3(64, NB), 256, 0, stream>>>(x, XsB);
  conv(w_cls1, b_cls1, XsB, XsA);
  conv(w_cls2, b_cls2, XsA, XsB);                    // cf = XsB
  head_cls_k<<<1444, 256, 0, stream>>>(XsB, w_clsh, b_clsh, clsp);
  decode_k<<<(NB * NPOS + 255) / 256, 256, 0, stream>>>(obj, clsp, regp, outb);
  nms_k<<<NB * NCLS, 64, 0, stream>>>(outb, outb + KEEP_OFF);
}

// Round 13
// 678.113 us; speedup vs baseline: 4.9021x; 1.0034x over previous
//
#include <hip/hip_runtime.h>
#include <hip/hip_bf16.h>
#include <stdint.h>

typedef __bf16 bf16x8 __attribute__((ext_vector_type(8)));
typedef float  f32x16 __attribute__((ext_vector_type(16)));

#define FMPX 19
#define NPOS 361
#define CCH  512
#define NB   16
#define NCLS 20
#define CONF_T 0.001f
#define NMS_TH 0.6f
#define BSCALE (32.0f/608.0f)

#define SC_OFF   (NB*NPOS*4)
#define CLS_OFF  (SC_OFF + NB*NPOS)
#define KEEP_OFF (CLS_OFF + NB*NPOS)

#define GSTR  3528                     // 441 rows * 8 ci elems
#define PLANE ((size_t)3612672)        // 16 b * 64 g * 3528 elems per split plane
#define WSL   294912                   // W elems per slice: 2pl*9t*32ch*512
#define XBUF  16384                    // 2pl * 2kh * 4096B
#define WBUF  18432                    // 2pl * 9tap * 2kh * 32co * 16B
#define WOFF  32768                    // 2*XBUF
#define SMEMB 69632                    // 2*XBUF + 2*WBUF (>= Lf 4*96*37*4=56832)

__device__ __forceinline__ void gl_lds16(const void* g, void* l) {
  __builtin_amdgcn_global_load_lds(
      (const __attribute__((address_space(1))) unsigned int*)g,
      (__attribute__((address_space(3))) unsigned int*)l, 16, 0, 0);
}
#define MFMA32(A,B,C) __builtin_amdgcn_mfma_f32_32x32x16_bf16(A,B,C,0,0,0)
#define SG(m,n) __builtin_amdgcn_sched_group_barrier(m, n, 0)
#define PRIO1 __builtin_amdgcn_s_setprio(1)
#define PRIO0 __builtin_amdgcn_s_setprio(0)

// ---------------- split x: f32 NCHW -> 2 bf16 planes [pl][b][g][row441][8ci]
__global__ void split_x_k(const float* __restrict__ x, __bf16* __restrict__ Xd) {
  __shared__ float sx[8][368];
  int g = blockIdx.x, b = blockIdx.y;
  int tid = threadIdx.x;
  for (int i = tid; i < 8*361; i += 256) {
    int ci = i / 361, p = i - ci*361;
    sx[ci][p] = x[((size_t)b*CCH + g*8 + ci)*NPOS + p];
  }
  __syncthreads();
  for (int row = tid; row < 441; row += 256) {
    int y = row/21, xx = row - y*21;
    bf16x8 oh = {}, om = {};
    if (y >= 1 && y <= 19 && xx >= 1 && xx <= 19) {
      int p = (y-1)*19 + xx - 1;
#pragma unroll
      for (int j = 0; j < 8; ++j) {
        float v = sx[j][p];
        __bf16 hh = (__bf16)v;
        oh[j] = hh; om[j] = (__bf16)(v - (float)hh);
      }
    }
    size_t o = (((size_t)b)*64 + g)*GSTR + (size_t)row*8;
    *(bf16x8*)(Xd + o)         = oh;
    *(bf16x8*)(Xd + PLANE + o) = om;
  }
}

// ---------------- weight repack+split: w[co][ci][3][3] f32 ->
//  Wg [slice16][pl2][tap9][chunk32][kh2][co32][8ci] bf16
__global__ void repack_k(const float* __restrict__ w, __bf16* __restrict__ Wg) {
  __shared__ float sw[32][145];
  int slice = blockIdx.x, chunk = blockIdx.y;
  int tid = threadIdx.x;
  for (int i = tid; i < 32*144; i += 256) {
    int cl = i / 144, r = i - cl*144;
    sw[cl][r] = w[((size_t)slice*32 + cl)*4608 + chunk*144 + r];
  }
  __syncthreads();
  for (int u = tid; u < 1152; u += 256) {
    int co = u & 31, kh = (u >> 5) & 1, pt = u >> 6;   // pt 0..17
    int tap = pt % 9, pl = pt / 9;
    bf16x8 o;
#pragma unroll
    for (int j = 0; j < 8; ++j) {
      float v = sw[co][(kh*8 + j)*9 + tap];
      __bf16 hh = (__bf16)v;
      o[j] = pl == 0 ? hh : (__bf16)(v - (float)hh);
    }
    *(bf16x8*)(Wg + (((size_t)(slice*2 + pl)*9 + tap)*32 + chunk)*512 + kh*256 + co*8) = o;
  }
}

// read 6 m-tile A fragments at per-tap offsets (+IMM selects plane: 0=h, 8192=m)
#define RD6X(SP, AT, IMM) do { \
  SP##0 = *(const bf16x8*)(Xc + AT##0 + (IMM)); \
  SP##1 = *(const bf16x8*)(Xc + AT##1 + (IMM)); \
  SP##2 = *(const bf16x8*)(Xc + AT##2 + (IMM)); \
  SP##3 = *(const bf16x8*)(Xc + AT##3 + (IMM)); \
  SP##4 = *(const bf16x8*)(Xc + AT##4 + (IMM)); \
  SP##5 = *(const bf16x8*)(Xc + AT##5 + (IMM)); } while (0)

#define CL(SP, BH_, BM_) do { \
  acc0 = MFMA32(SP##0, BH_, acc0); acc1 = MFMA32(SP##1, BH_, acc1); \
  acc2 = MFMA32(SP##2, BH_, acc2); acc3 = MFMA32(SP##3, BH_, acc3); \
  acc4 = MFMA32(SP##4, BH_, acc4); acc5 = MFMA32(SP##5, BH_, acc5); \
  acc0 = MFMA32(SP##0, BM_, acc0); acc1 = MFMA32(SP##1, BM_, acc1); \
  acc2 = MFMA32(SP##2, BM_, acc2); acc3 = MFMA32(SP##3, BM_, acc3); \
  acc4 = MFMA32(SP##4, BM_, acc4); acc5 = MFMA32(SP##5, BM_, acc5); } while (0)

#define CLH(SP, B_) do { \
  acc0 = MFMA32(SP##0, B_, acc0); acc1 = MFMA32(SP##1, B_, acc1); \
  acc2 = MFMA32(SP##2, B_, acc2); acc3 = MFMA32(SP##3, B_, acc3); \
  acc4 = MFMA32(SP##4, B_, acc4); acc5 = MFMA32(SP##5, B_, acc5); } while (0)

#define STO(A, MTL) do { _Pragma("unroll") \
  for (int r = 0; r < 16; ++r) { \
    Lf[wq*3552 + ((MTL)*32 + 4*kh + (r & 3) + 8*(r >> 2))*37 + col] = (A)[r]; } } while (0)

// ---------------- 3x3 conv: bf16x2, 4 products {hh,hm,mh,mm}
// grid 512 (b,slice,h); block 256 = 4 waves, tap-major roles.
// Depth-2 read-ahead: G0+G1 (14 ds_reads) up front; per-cluster SGB script
// interleaves cluster k's 12 MFMA with cluster k+2's reads so every wait is
// counted (reads issued >=1 full cluster earlier). 3 rotating A register sets.
__global__ __launch_bounds__(256, 2) void conv3x3_mfma(
    const __bf16* __restrict__ Xs, const __bf16* __restrict__ Wg,
    const float* __restrict__ bias, __bf16* __restrict__ Xd)
{
  __shared__ __attribute__((aligned(16))) char smem[SMEMB];
  const int tid = threadIdx.x;
  const int bid = blockIdx.x;
  const int b = bid & 15, slice = (bid >> 4) & 15, h = bid >> 8;
  const int lane = tid & 63;
  const int wq = __builtin_amdgcn_readfirstlane(tid >> 6);
  const int col = lane & 31, kh = lane >> 5;
  const int kh4096 = kh*4096;
  const int PB = h*190, CNT = h ? 171 : 190;
  const int PEND = PB + CNT - 1;
  const int clampU = h ? 230 : 251;

  // per-m-tile base LDS offsets (local padded row * 16)
  int ab0, ab1, ab2, ab3, ab4, ab5;
  {
    int ao[6];
#pragma unroll
    for (int mt = 0; mt < 6; ++mt) {
      int p = PB + mt*32 + col; if (p > PEND) p = PEND;
      int pp = p + 2*(p/19) + 22;
      ao[mt] = (pp - h*210)*16;
    }
    ab0 = ao[0]; ab1 = ao[1]; ab2 = ao[2]; ab3 = ao[3]; ab4 = ao[4]; ab5 = ao[5];
  }
  const int boff = kh*512 + col*16;

  // per-wave tap assignment
  const int goffs[9] = {-352,-336,-320,-16,0,16,320,336,352};
  const int t0 = 2*wq, t1 = t0 + 1;
  const int g0 = goffs[t0], g1 = goffs[t1];
  const int a8im = 352 + ((wq & 2) ? 8192 : 0);   // tap8 A plane by role
  const int t0a0 = ab0+g0, t0a1 = ab1+g0, t0a2 = ab2+g0,
            t0a3 = ab3+g0, t0a4 = ab4+g0, t0a5 = ab5+g0;
  const int t1a0 = ab0+g1, t1a1 = ab1+g1, t1a2 = ab2+g1,
            t1a3 = ab3+g1, t1a4 = ab4+g1, t1a5 = ab5+g1;
  const int t8a0 = ab0+a8im, t8a1 = ab1+a8im, t8a2 = ab2+a8im,
            t8a3 = ab3+a8im, t8a4 = ab4+a8im, t8a5 = ab5+a8im;
  const int wb0 = t0*1024 + boff, wb1 = t1*1024 + boff;
  const int wb8 = 8192 + boff + ((wq & 1) ? 9216 : 0);   // tap8 B plane by role

  // X staging: 4 insts/thread, slot r -> (pl,khs)=(r>>1,r&1), column block j=wq
  int ux = wq*64 + lane; if (ux > clampU) ux = clampU;
  const __bf16* xsb = Xs + (size_t)b*64*GSTR + (size_t)(h*210 + ux)*8;
  // W staging: 5 uniform slots/wave, wk = (wq*5+q) % 18 (wave3 dups 0,1 -- benign)
  const __bf16* wsb = Wg + (size_t)slice*WSL + (size_t)lane*8;
  int wsrc0, wsrc1, wsrc2, wsrc3, wsrc4;
  int wdst0, wdst1, wdst2, wdst3, wdst4;
  {
    int ws[5], wd[5];
#pragma unroll
    for (int q = 0; q < 5; ++q) {
      int wk = (wq*5 + q) % 18;
      int pl = wk > 8 ? 1 : 0, tap = wk - 9*pl;
      ws[q] = ((pl*9 + tap)*32)*512;
      wd[q] = WOFF + pl*9216 + tap*1024;
    }
    wsrc0 = ws[0]; wsrc1 = ws[1]; wsrc2 = ws[2]; wsrc3 = ws[3]; wsrc4 = ws[4];
    wdst0 = wd[0]; wdst1 = wd[1]; wdst2 = wd[2]; wdst3 = wd[3]; wdst4 = wd[4];
  }

  auto stage = [&](int c1, int buf) {
    const __bf16* xs = xsb + (size_t)(2*c1)*GSTR;
    char* xd = smem + (buf ? XBUF : 0) + wq*1024;
    gl_lds16(xs,                    xd);
    gl_lds16(xs + GSTR,             xd + 4096);
    gl_lds16(xs + PLANE,            xd + 8192);
    gl_lds16(xs + PLANE + GSTR,     xd + 12288);
    const __bf16* wsc = wsb + (size_t)c1*512;
    char* wb = smem + (buf ? WBUF : 0);
    gl_lds16(wsc + wsrc0, wb + wdst0);
    gl_lds16(wsc + wsrc1, wb + wdst1);
    gl_lds16(wsc + wsrc2, wb + wdst2);
    gl_lds16(wsc + wsrc3, wb + wdst3);
    gl_lds16(wsc + wsrc4, wb + wdst4);
  };

  f32x16 acc0 = {}, acc1 = {}, acc2 = {}, acc3 = {}, acc4 = {}, acc5 = {};

  stage(0, 0);
  __syncthreads();

  for (int c = 0; c < 32; ++c) {
    const char* Xc = smem + (c & 1)*XBUF + kh4096;
    const char* Wc = smem + WOFF + (c & 1)*WBUF;
    const int cn = (c < 31) ? (c + 1) : 31;    // branchless dup of last chunk

    bf16x8 Aa0, Aa1, Aa2, Aa3, Aa4, Aa5;
    bf16x8 Ab0, Ab1, Ab2, Ab3, Ab4, Ab5;
    bf16x8 Ac0, Ac1, Ac2, Ac3, Ac4, Ac5;
    bf16x8 B0h, B0m, B1h, B1m, B8v;

    // front: G0 = Ah(t0)+B(t0) [8 ds], G1 = Am(t0) [6 ds]
    RD6X(Aa, t0a, 0);
    B0h = *(const bf16x8*)(Wc + wb0);
    B0m = *(const bf16x8*)(Wc + wb0 + 9216);
    RD6X(Ab, t0a, 8192);
    // stage c+1   [9 vmem]
    stage(cn, (c + 1) & 1);
    PRIO1;
    // C0: t0 hh,hm  ||  G2 = Ah(t1)+B(t1) -> Ac,B1   [8 ds]
    RD6X(Ac, t1a, 0);
    B1h = *(const bf16x8*)(Wc + wb1);
    B1m = *(const bf16x8*)(Wc + wb1 + 9216);
    CL(Aa, B0h, B0m);
    // C1: t0 mh,mm  ||  G3 = Am(t1) -> Aa   [6 ds]
    RD6X(Aa, t1a, 8192);
    CL(Ab, B0h, B0m);
    // C2: t1 hh,hm  ||  G4 = A(t8)+B(t8) -> Ab,B8   [7 ds]
    RD6X(Ab, t8a, 0);
    B8v = *(const bf16x8*)(Wc + wb8);
    CL(Ac, B1h, B1m);
    // C3: t1 mh,mm
    CL(Aa, B1h, B1m);
    // C4: tap8 product
    CLH(Ab, B8v);
    PRIO0;

    // ---- schedule script
    SG(0x100, 14);                // G0+G1: 14 ds_read
    SG(0x70, 9);                  // 9 global_load_lds
#pragma unroll
    for (int i = 0; i < 4; ++i) { SG(8, 3); SG(0x100, 2); }   // C0 || G2 (8 ds)
#pragma unroll
    for (int i = 0; i < 6; ++i) { SG(8, 2); SG(0x100, 1); }   // C1 || G3 (6 ds)
#pragma unroll
    for (int i = 0; i < 7; ++i) { SG(8, 1); SG(0x100, 1); }   // C2 || G4 (7 ds)
    SG(8, 5);                     // C2 tail
    SG(8, 18);                    // C3 + C4
    __syncthreads();
  }

  // epilogue: 4 partials in Lf[4][96][37] (pad 37 -> conflict-free combine)
  float* Lf = (float*)smem;
#pragma unroll
  for (int half = 0; half < 2; ++half) {
    if (half == 0) { STO(acc0, 0); STO(acc1, 1); STO(acc2, 2); }
    else           { STO(acc3, 0); STO(acc4, 1); STO(acc5, 2); }
    __syncthreads();
    for (int u = tid; u < 768; u += 256) {
      int pl = u / 384, rem = u - pl*384;
      int gq = rem / 96, lp = rem - gq*96;
      int lpos = half*96 + lp;
      if (lpos < CNT) {
        int p = PB + lpos;
        int pp = p + 2*(p/19) + 22;
        const float* bb = bias + slice*32 + gq*8;
        bf16x8 o;
#pragma unroll
        for (int j = 0; j < 8; ++j) {
          int coix = lp*37 + gq*8 + j;
          float v = Lf[coix] + Lf[3552 + coix] + Lf[7104 + coix] + Lf[10656 + coix] + bb[j];
          v = v > 0.f ? v : 0.1f*v;
          __bf16 hh = (__bf16)v;
          o[j] = pl == 0 ? hh : (__bf16)(v - (float)hh);
        }
        *(bf16x8*)(Xd + (((size_t)pl*16 + b)*64 + slice*4 + gq)*GSTR + (size_t)pp*8) = o;
      }
    }
    __syncthreads();
  }

  // zero output halo rows for this h-half (halo columns are x=0 and x=20)
  const int nh = h ? 39 : 41;
  for (int u = tid; u < 8*nh; u += 256) {
    int pl = u / (4*nh); int rem = u - pl*4*nh;
    int gq = rem / nh; int ci2 = rem - gq*nh;
    int rowpos;
    if (ci2 < 21) rowpos = h ? (420 + ci2) : ci2;
    else { int q = ci2 - 21; rowpos = ((h ? 11 : 1) + (q >> 1))*21 + 20*(q & 1); }
    bf16x8 z = {};
    *(bf16x8*)(Xd + (((size_t)pl*16 + b)*64 + slice*4 + gq)*GSTR + (size_t)rowpos*8) = z;
  }
}

// ---------------- 1x1 heads on split planes ----------------
__global__ __launch_bounds__(256) void head_rf_k(
    const __bf16* __restrict__ F, const float* __restrict__ wobj,
    const float* __restrict__ bobj, const float* __restrict__ wreg,
    const float* __restrict__ breg, float* __restrict__ obj, float* __restrict__ regp)
{
  int gw = blockIdx.x*4 + (threadIdx.x >> 6);
  if (gw >= NB*NPOS) return;
  int lane = threadIdx.x & 63;
  int b = gw / NPOS, p = gw % NPOS;
  int pp = p + 2*(p/19) + 22;
  const __bf16* base = F + (((size_t)b)*64 + lane)*GSTR + (size_t)pp*8;
  bf16x8 v0 = *(const bf16x8*)base;
  bf16x8 v1 = *(const bf16x8*)(base + PLANE);
  float f[8];
#pragma unroll
  for (int j = 0; j < 8; ++j) f[j] = (float)v0[j] + (float)v1[j];
#pragma unroll
  for (int o = 0; o < 5; ++o) {
    const float* wp = (o == 0) ? wobj : wreg + (o-1)*CCH;
    float4 wa = *(const float4*)(wp + lane*8);
    float4 wb = *(const float4*)(wp + lane*8 + 4);
    float s2 = f[0]*wa.x + f[1]*wa.y + f[2]*wa.z + f[3]*wa.w
             + f[4]*wb.x + f[5]*wb.y + f[6]*wb.z + f[7]*wb.w;
#pragma unroll
    for (int d = 32; d; d >>= 1) s2 += __shfl_xor(s2, d);
    if (lane == 0) {
      if (o == 0) obj[gw] = s2 + bobj[0];
      else regp[(size_t)gw*4 + (o-1)] = s2 + breg[o-1];
    }
  }
}

__global__ __launch_bounds__(256) void head_cls_k(
    const __bf16* __restrict__ F, const float* __restrict__ wcls,
    const float* __restrict__ bcls, float* __restrict__ clsp)
{
  int gw = blockIdx.x*4 + (threadIdx.x >> 6);
  if (gw >= NB*NPOS) return;
  int lane = threadIdx.x & 63;
  int b = gw / NPOS, p = gw % NPOS;
  int pp = p + 2*(p/19) + 22;
  const __bf16* base = F + (((size_t)b)*64 + lane)*GSTR + (size_t)pp*8;
  bf16x8 v0 = *(const bf16x8*)base;
  bf16x8 v1 = *(const bf16x8*)(base + PLANE);
  float f[8];
#pragma unroll
  for (int j = 0; j < 8; ++j) f[j] = (float)v0[j] + (float)v1[j];
#pragma unroll
  for (int o = 0; o < NCLS; ++o) {
    const float* wp = wcls + o*CCH;
    float4 wa = *(const float4*)(wp + lane*8);
    float4 wb = *(const float4*)(wp + lane*8 + 4);
    float s2 = f[0]*wa.x + f[1]*wa.y + f[2]*wa.z + f[3]*wa.w
             + f[4]*wb.x + f[5]*wb.y + f[6]*wb.z + f[7]*wb.w;
#pragma unroll
    for (int d = 32; d; d >>= 1) s2 += __shfl_xor(s2, d);
    if (lane == 0) clsp[(size_t)gw*NCLS + o] = s2 + bcls[o];
  }
}

// ---------------- decode boxes + scores + argmax -------------------------
__global__ void decode_k(const float* __restrict__ obj, const float* __restrict__ clsp,
                         const float* __restrict__ regp, float* __restrict__ outb)
{
  int i = blockIdx.x * 256 + threadIdx.x;
  if (i >= NB * NPOS) return;
  int p = i % NPOS;
  float gx = (float)(p % FMPX), gy = (float)(p / FMPX);
  float4 rg = *(const float4*)&regp[(size_t)i * 4];
  float cx = 1.f / (1.f + expf(-rg.x)) + gx;
  float cy = 1.f / (1.f + expf(-rg.y)) + gy;
  float whw = expf(rg.z), whh = expf(rg.w);
  float x1 = fminf(fmaxf((cx - whw * 0.5f) * BSCALE, 0.f), 1.f);
  float y1 = fminf(fmaxf((cy - whh * 0.5f) * BSCALE, 0.f), 1.f);
  float x2 = fminf(fmaxf((cx + whw * 0.5f) * BSCALE, 0.f), 1.f);
  float y2 = fminf(fmaxf((cy + whh * 0.5f) * BSCALE, 0.f), 1.f);
  outb[(size_t)i * 4 + 0] = x1; outb[(size_t)i * 4 + 1] = y1;
  outb[(size_t)i * 4 + 2] = x2; outb[(size_t)i * 4 + 3] = y2;

  float so = 1.f / (1.f + expf(-obj[i]));
  float cv[20];
  const float4* cp = (const float4*)&clsp[(size_t)i * 20];
#pragma unroll
  for (int q = 0; q < 5; q++) {
    float4 v4 = cp[q];
    cv[q * 4] = v4.x; cv[q * 4 + 1] = v4.y; cv[q * 4 + 2] = v4.z; cv[q * 4 + 3] = v4.w;
  }
  float mx = cv[0];
#pragma unroll
  for (int c = 1; c < 20; c++) mx = fmaxf(mx, cv[c]);
  float sum = 0.f;
#pragma unroll
  for (int c = 0; c < 20; c++) { cv[c] = expf(cv[c] - mx); sum += cv[c]; }
  float inv = so / sum;
  float best = -1.f; int bi = 0;
#pragma unroll
  for (int c = 0; c < 20; c++) { float s = cv[c] * inv; if (s > best) { best = s; bi = c; } }
  outb[SC_OFF + i] = best;
  outb[CLS_OFF + i] = (float)bi;
  outb[KEEP_OFF + i] = 0.f;
}

// ---------------- per (batch,class) greedy NMS ----------------------------
__device__ inline unsigned ordf(float f) {
  unsigned u = __float_as_uint(f);
  return (u & 0x80000000u) ? ~u : (u | 0x80000000u);
}

__global__ __launch_bounds__(64) void nms_k(const float* __restrict__ outb, float* __restrict__ keep_out)
{
  int b = blockIdx.x / NCLS, c = blockIdx.x % NCLS;
  int lane = threadIdx.x;
  __shared__ unsigned long long keys[512];
  __shared__ float bx1[384], by1[384], bx2[384], by2[384], bar[384];
  __shared__ unsigned kp[384];
  __shared__ int sj[384];

  for (int i = lane; i < 512; i += 64) {
    unsigned long long key = 0ULL;
    if (i < NPOS) {
      float sc = outb[SC_OFF + b * NPOS + i];
      int ci = (int)outb[CLS_OFF + b * NPOS + i];
      float s = (ci == c && sc >= CONF_T) ? sc : -1.0f;
      key = ((unsigned long long)ordf(s) << 32) | (unsigned)(~(unsigned)i);
    }
    keys[i] = key;
  }
  __syncthreads();
  for (int kk = 2; kk <= 512; kk <<= 1) {
    for (int jj = kk >> 1; jj > 0; jj >>= 1) {
      for (int i = lane; i < 512; i += 64) {
        int l2 = i ^ jj;
        if (l2 > i) {
          unsigned long long a = keys[i], bb2 = keys[l2];
          bool dir = (i & kk) == 0;
          bool sw = dir ? (a < bb2) : (a > bb2);
          if (sw) { keys[i] = bb2; keys[l2] = a; }
        }
      }
      __syncthreads();
    }
  }
  unsigned ordc = ordf(CONF_T);
  int nvalid = 0;
  for (int i = lane; i < 384; i += 64) {
    unsigned long long key = keys[i];
    unsigned hi = (unsigned)(key >> 32);
    int j = (int)(~(unsigned)key);
    bool valid = (key != 0ULL) && (hi >= ordc);
    kp[i] = valid ? 1u : 0u;
    if (valid) {
      const float* bp = &outb[(size_t)(b * NPOS + j) * 4];
      float x1 = bp[0], y1 = bp[1], x2 = bp[2], y2 = bp[3];
      bx1[i] = x1; by1[i] = y1; bx2[i] = x2; by2[i] = y2;
      bar[i] = (x2 - x1) * (y2 - y1);
      sj[i] = j;
    } else { bx1[i] = 0; by1[i] = 0; bx2[i] = 0; by2[i] = 0; bar[i] = 0; sj[i] = 0; }
    nvalid += __popcll(__ballot(valid));
  }
  __syncthreads();
  for (int i = 0; i < nvalid; ++i) {
    if (kp[i]) {
      float x1i = bx1[i], y1i = by1[i], x2i = bx2[i], y2i = by2[i], ai = bar[i];
      for (int j2 = i + 1 + lane; j2 < nvalid; j2 += 64) {
        if (kp[j2]) {
          float ww = fmaxf(1e-28f, fminf(x2i, bx2[j2]) - fmaxf(x1i, bx1[j2]));
          float hh = fmaxf(1e-28f, fminf(y2i, by2[j2]) - fmaxf(y1i, by1[j2]));
          float inter = ww * hh;
          float iou = inter / (ai + bar[j2] - inter + 1e-14f);
          if (iou > NMS_TH) kp[j2] = 0u;
        }
      }
    }
    __syncthreads();
  }
  for (int i = lane; i < 384; i += 64)
    if (kp[i]) keep_out[b * NPOS + sj[i]] = 1.0f;
}

extern "C" void kernel_launch(void* const* d_in, const int* in_sizes, int n_in,
                              void* d_out, int out_size, void* d_ws, size_t ws_size,
                              hipStream_t stream)
{
  const float* x      = (const float*)d_in[0];
  const float* w_cls1 = (const float*)d_in[1];  const float* b_cls1 = (const float*)d_in[2];
  const float* w_cls2 = (const float*)d_in[3];  const float* b_cls2 = (const float*)d_in[4];
  const float* w_reg1 = (const float*)d_in[5];  const float* b_reg1 = (const float*)d_in[6];
  const float* w_reg2 = (const float*)d_in[7];  const float* b_reg2 = (const float*)d_in[8];
  const float* w_reg3 = (const float*)d_in[9];  const float* b_reg3 = (const float*)d_in[10];
  const float* w_reg4 = (const float*)d_in[11]; const float* b_reg4 = (const float*)d_in[12];
  const float* w_obj  = (const float*)d_in[13]; const float* b_obj  = (const float*)d_in[14];
  const float* w_clsh = (const float*)d_in[15]; const float* b_clsh = (const float*)d_in[16];
  const float* w_regh = (const float*)d_in[17]; const float* b_regh = (const float*)d_in[18];
  float* outb = (float*)d_out;

  __bf16* Xs0 = (__bf16*)d_ws;          // preserved split of x (never overwritten)
  __bf16* XsA = Xs0 + 2*PLANE;
  __bf16* XsB = XsA + 2*PLANE;
  __bf16* Wg  = XsB + 2*PLANE;
  float* obj  = (float*)(Wg + (size_t)16*WSL);
  float* regp = obj + NB*NPOS;
  float* clsp = regp + (size_t)NB*NPOS*4;

  auto conv = [&](const float* wsrc, const float* bsrc, const __bf16* src, __bf16* dst) {
    repack_k<<<dim3(16, 32), 256, 0, stream>>>(wsrc, Wg);
    conv3x3_mfma<<<512, 256, 0, stream>>>(src, Wg, bsrc, dst);
  };

  split_x_k<<<dim3(64, NB), 256, 0, stream>>>(x, Xs0);
  conv(w_reg1, b_reg1, Xs0, XsA);
  conv(w_reg2, b_reg2, XsA, XsB);
  conv(w_reg3, b_reg3, XsB, XsA);
  conv(w_reg4, b_reg4, XsA, XsB);                    // rf = XsB
  head_rf_k<<<1444, 256, 0, stream>>>(XsB, w_obj, b_obj, w_regh, b_regh, obj, regp);
  conv(w_cls1, b_cls1, Xs0, XsA);
  conv(w_cls2, b_cls2, XsA, XsB);                    // cf = XsB
  head_cls_k<<<1444, 256, 0, stream>>>(XsB, w_clsh, b_clsh, clsp);
  decode_k<<<(NB * NPOS + 255) / 256, 256, 0, stream>>>(obj, clsp, regp, outb);
  nms_k<<<NB * NCLS, 64, 0, stream>>>(outb, outb + KEEP_OFF);
}